// Round 1
// baseline (24305.754 us; speedup 1.0000x reference)
//
#include <hip/hip_runtime.h>
#include <math.h>

// Problem constants (from reference)
#define Bn 64      // batch
#define Lq 128     // output_length (= attn logits width)
#define En 512     // emb dim
#define Hn 512     // hidden
#define Vn 32000   // vocab
#define Tn 127     // steps = L-1

// Z layout per step: [Bn][3200]
//   cols [0,128)    : attn logits (incl. b_attn)
//   cols [128,1664) : gh = h @ W_hh.T + b_hh   (r: +0, z: +512, n: +1024)
//   cols [1664,3200): gi = x @ W_ih.T + b_ih   (r: +0, z: +512, n: +1024)
#define ZC 3200

// ws layout (float offsets)
#define OFF_LOSS 0
#define OFF_HA   64
#define OFF_HB   (OFF_HA + Bn*Hn)            // 32832
#define OFF_Z    (OFF_HB + Bn*Hn)            // 65600
#define OFF_PM   (OFF_Z + Bn*ZC)             // 270400 : pmax[250][64]
#define OFF_PS   (OFF_PM + 250*Bn)           // 286400 : psum[250][64]

// LDS strides (floats). PA*4 and PW*4 are multiples of 16B so float4 LDS reads are aligned.
#define PA 68
#define PW 132

__global__ void init_kernel(float* __restrict__ ws) {
    int i = blockIdx.x * 256 + threadIdx.x;
    if (i < Bn * Hn) ws[OFF_HA + i] = 0.0f;
    if (i == 0) ws[OFF_LOSS] = 0.0f;
}

// ---------------------------------------------------------------------------
// z_kernel: 25 blocks x 256 threads. Block 0: attn logits (K=1024, A=[dec_in|h]).
// Blocks 1..12: gh (A=h). Blocks 13..24: gi (A=emb[idx[:,step]]).
// Each block computes a 64x128 tile; thread (tr,tc) computes 4 rows x 8 cols.
// ---------------------------------------------------------------------------
__global__ __launch_bounds__(256) void z_kernel(
    const float* __restrict__ h,      // [64][512] current hidden
    const int*   __restrict__ idx,    // [64][128] decoder_inputs
    const float* __restrict__ emb,    // [32000][512]
    const float* __restrict__ W_attn, const float* __restrict__ b_attn,
    const float* __restrict__ W_ih,   const float* __restrict__ b_ih,
    const float* __restrict__ W_hh,   const float* __restrict__ b_hh,
    float* __restrict__ Z, int step)
{
    const int t  = threadIdx.x;
    const int tr = t >> 4, tc = t & 15;
    const int blk = blockIdx.x;

    int group, cbase, K, zbase;
    const float* Wb; const float* bias;
    if (blk == 0)       { group = 0; cbase = 0;              K = 1024; Wb = W_attn; bias = b_attn; zbase = 0; }
    else if (blk <= 12) { group = 1; cbase = (blk - 1) * 128; K = 512; Wb = W_hh;   bias = b_hh;   zbase = 128; }
    else                { group = 2; cbase = (blk - 13) * 128; K = 512; Wb = W_ih;  bias = b_ih;   zbase = 1664; }

    __shared__ float As[32 * PA];   // [kk][row]
    __shared__ float Ws[32 * PW];   // [kk][col]

    float acc[4][8];
    #pragma unroll
    for (int q = 0; q < 4; q++)
        #pragma unroll
        for (int j = 0; j < 8; j++) acc[q][j] = 0.0f;

    const int jprev = (step > 0) ? (step - 1) : 0;
    const int ab = t & 63, kq = t >> 6;   // A staging: row ab, k-quarter kq
    const int wc = t >> 1, wh = t & 1;    // W staging: col wc, k-half wh

    for (int k0 = 0; k0 < K; k0 += 32) {
        // ---- stage A chunk: As[kk][row], kk = k - k0 (transposed for b128 row reads)
        {
            const int kb = k0 + kq * 8;
            const float* ap;
            if (group == 0) {
                if (kb < 512) ap = emb + (size_t)idx[ab * Lq + jprev] * En + kb;
                else          ap = h + ab * Hn + (kb - 512);
            } else if (group == 1) {
                ap = h + ab * Hn + kb;
            } else {
                ap = emb + (size_t)idx[ab * Lq + step] * En + kb;
            }
            const float4 v0 = *reinterpret_cast<const float4*>(ap);
            const float4 v1 = *reinterpret_cast<const float4*>(ap + 4);
            const int kk = kq * 8;
            As[(kk + 0) * PA + ab] = v0.x;  As[(kk + 1) * PA + ab] = v0.y;
            As[(kk + 2) * PA + ab] = v0.z;  As[(kk + 3) * PA + ab] = v0.w;
            As[(kk + 4) * PA + ab] = v1.x;  As[(kk + 5) * PA + ab] = v1.y;
            As[(kk + 6) * PA + ab] = v1.z;  As[(kk + 7) * PA + ab] = v1.w;
        }
        // ---- stage W chunk: Ws[kk][col] (transposed)
        {
            const float* wp = Wb + (size_t)(cbase + wc) * K + k0 + wh * 16;
            const float4 w0 = reinterpret_cast<const float4*>(wp)[0];
            const float4 w1 = reinterpret_cast<const float4*>(wp)[1];
            const float4 w2 = reinterpret_cast<const float4*>(wp)[2];
            const float4 w3 = reinterpret_cast<const float4*>(wp)[3];
            const int kk = wh * 16;
            Ws[(kk + 0 ) * PW + wc] = w0.x; Ws[(kk + 1 ) * PW + wc] = w0.y;
            Ws[(kk + 2 ) * PW + wc] = w0.z; Ws[(kk + 3 ) * PW + wc] = w0.w;
            Ws[(kk + 4 ) * PW + wc] = w1.x; Ws[(kk + 5 ) * PW + wc] = w1.y;
            Ws[(kk + 6 ) * PW + wc] = w1.z; Ws[(kk + 7 ) * PW + wc] = w1.w;
            Ws[(kk + 8 ) * PW + wc] = w2.x; Ws[(kk + 9 ) * PW + wc] = w2.y;
            Ws[(kk + 10) * PW + wc] = w2.z; Ws[(kk + 11) * PW + wc] = w2.w;
            Ws[(kk + 12) * PW + wc] = w3.x; Ws[(kk + 13) * PW + wc] = w3.y;
            Ws[(kk + 14) * PW + wc] = w3.z; Ws[(kk + 15) * PW + wc] = w3.w;
        }
        __syncthreads();
        #pragma unroll 4
        for (int kk = 0; kk < 32; kk++) {
            const float4 av = *reinterpret_cast<const float4*>(&As[kk * PA + tr * 4]);
            const float4 w0 = *reinterpret_cast<const float4*>(&Ws[kk * PW + tc * 8]);
            const float4 w1 = *reinterpret_cast<const float4*>(&Ws[kk * PW + tc * 8 + 4]);
            const float a0 = av.x, a1 = av.y, a2 = av.z, a3 = av.w;
            const float w[8] = {w0.x, w0.y, w0.z, w0.w, w1.x, w1.y, w1.z, w1.w};
            #pragma unroll
            for (int j = 0; j < 8; j++) {
                acc[0][j] = fmaf(a0, w[j], acc[0][j]);
                acc[1][j] = fmaf(a1, w[j], acc[1][j]);
                acc[2][j] = fmaf(a2, w[j], acc[2][j]);
                acc[3][j] = fmaf(a3, w[j], acc[3][j]);
            }
        }
        __syncthreads();
    }

    #pragma unroll
    for (int q = 0; q < 4; q++) {
        const int row = tr * 4 + q;
        #pragma unroll
        for (int j = 0; j < 8; j++) {
            const int lc = tc * 8 + j;                 // local col within 128-tile
            Z[row * ZC + zbase + cbase + lc] = acc[q][j] + bias[cbase + lc];
        }
    }
}

// ---------------------------------------------------------------------------
// gates_softmax_kernel: 64 blocks (one per batch row) x 128 threads.
// Softmax over attn logits -> attns output; GRU gates -> h_new.
// ---------------------------------------------------------------------------
__global__ __launch_bounds__(128) void gates_softmax_kernel(
    const float* __restrict__ Z, const float* __restrict__ h,
    float* __restrict__ hn, float* __restrict__ out_attn,
    float* __restrict__ out_hfin, int step, int last)
{
    const int b = blockIdx.x;
    const int t = threadIdx.x;
    __shared__ float red[128];

    // softmax over Z[b][0:128]
    const float x = Z[b * ZC + t];
    red[t] = x; __syncthreads();
    for (int s = 64; s > 0; s >>= 1) {
        if (t < s) red[t] = fmaxf(red[t], red[t + s]);
        __syncthreads();
    }
    const float M = red[0];
    __syncthreads();
    const float e = expf(x - M);
    red[t] = e; __syncthreads();
    for (int s = 64; s > 0; s >>= 1) {
        if (t < s) red[t] += red[t + s];
        __syncthreads();
    }
    const float S = red[0];
    out_attn[((size_t)step * Bn + b) * Lq + t] = e / S;

    // GRU gates (PyTorch order r,z,n); biases already folded into Z
    #pragma unroll
    for (int q = 0; q < 4; q++) {
        const int u = t + q * 128;
        const float ghr = Z[b * ZC + 128  + u];
        const float ghz = Z[b * ZC + 640  + u];
        const float ghn = Z[b * ZC + 1152 + u];
        const float gir = Z[b * ZC + 1664 + u];
        const float giz = Z[b * ZC + 2176 + u];
        const float gin = Z[b * ZC + 2688 + u];
        const float r  = 1.0f / (1.0f + expf(-(gir + ghr)));
        const float zg = 1.0f / (1.0f + expf(-(giz + ghz)));
        const float n  = tanhf(gin + r * ghn);
        const float hv = h[b * Hn + u];
        const float hnew = (1.0f - zg) * n + zg * hv;
        hn[b * Hn + u] = hnew;
        if (last) out_hfin[b * Hn + u] = hnew;
    }
}

// ---------------------------------------------------------------------------
// logits_kernel: 250 blocks x 256 threads. Block c: cols [c*128, c*128+128).
// Computes logits tile (h_new @ W_out.T + b_out), emits per-block partial
// (rowmax, sum exp) for logsumexp. On last step also writes raw logits tile.
// ---------------------------------------------------------------------------
__global__ __launch_bounds__(256) void logits_kernel(
    const float* __restrict__ hn, const float* __restrict__ Wout,
    const float* __restrict__ bout, float* __restrict__ pmax,
    float* __restrict__ psum, float* __restrict__ out_logits, int last)
{
    const int t  = threadIdx.x;
    const int tr = t >> 4, tc = t & 15;
    const int cbase = blockIdx.x * 128;

    __shared__ float As[32 * PA];
    __shared__ float Ws[32 * PW];

    float acc[4][8];
    #pragma unroll
    for (int q = 0; q < 4; q++)
        #pragma unroll
        for (int j = 0; j < 8; j++) acc[q][j] = 0.0f;

    const int ab = t & 63, kq = t >> 6;
    const int wc = t >> 1, wh = t & 1;

    for (int k0 = 0; k0 < 512; k0 += 32) {
        {
            const float* ap = hn + ab * Hn + k0 + kq * 8;
            const float4 v0 = *reinterpret_cast<const float4*>(ap);
            const float4 v1 = *reinterpret_cast<const float4*>(ap + 4);
            const int kk = kq * 8;
            As[(kk + 0) * PA + ab] = v0.x;  As[(kk + 1) * PA + ab] = v0.y;
            As[(kk + 2) * PA + ab] = v0.z;  As[(kk + 3) * PA + ab] = v0.w;
            As[(kk + 4) * PA + ab] = v1.x;  As[(kk + 5) * PA + ab] = v1.y;
            As[(kk + 6) * PA + ab] = v1.z;  As[(kk + 7) * PA + ab] = v1.w;
        }
        {
            const float* wp = Wout + (size_t)(cbase + wc) * 512 + k0 + wh * 16;
            const float4 w0 = reinterpret_cast<const float4*>(wp)[0];
            const float4 w1 = reinterpret_cast<const float4*>(wp)[1];
            const float4 w2 = reinterpret_cast<const float4*>(wp)[2];
            const float4 w3 = reinterpret_cast<const float4*>(wp)[3];
            const int kk = wh * 16;
            Ws[(kk + 0 ) * PW + wc] = w0.x; Ws[(kk + 1 ) * PW + wc] = w0.y;
            Ws[(kk + 2 ) * PW + wc] = w0.z; Ws[(kk + 3 ) * PW + wc] = w0.w;
            Ws[(kk + 4 ) * PW + wc] = w1.x; Ws[(kk + 5 ) * PW + wc] = w1.y;
            Ws[(kk + 6 ) * PW + wc] = w1.z; Ws[(kk + 7 ) * PW + wc] = w1.w;
            Ws[(kk + 8 ) * PW + wc] = w2.x; Ws[(kk + 9 ) * PW + wc] = w2.y;
            Ws[(kk + 10) * PW + wc] = w2.z; Ws[(kk + 11) * PW + wc] = w2.w;
            Ws[(kk + 12) * PW + wc] = w3.x; Ws[(kk + 13) * PW + wc] = w3.y;
            Ws[(kk + 14) * PW + wc] = w3.z; Ws[(kk + 15) * PW + wc] = w3.w;
        }
        __syncthreads();
        #pragma unroll 4
        for (int kk = 0; kk < 32; kk++) {
            const float4 av = *reinterpret_cast<const float4*>(&As[kk * PA + tr * 4]);
            const float4 w0 = *reinterpret_cast<const float4*>(&Ws[kk * PW + tc * 8]);
            const float4 w1 = *reinterpret_cast<const float4*>(&Ws[kk * PW + tc * 8 + 4]);
            const float a0 = av.x, a1 = av.y, a2 = av.z, a3 = av.w;
            const float w[8] = {w0.x, w0.y, w0.z, w0.w, w1.x, w1.y, w1.z, w1.w};
            #pragma unroll
            for (int j = 0; j < 8; j++) {
                acc[0][j] = fmaf(a0, w[j], acc[0][j]);
                acc[1][j] = fmaf(a1, w[j], acc[1][j]);
                acc[2][j] = fmaf(a2, w[j], acc[2][j]);
                acc[3][j] = fmaf(a3, w[j], acc[3][j]);
            }
        }
        __syncthreads();
    }

    // bias + (optional) store + per-row partial logsumexp
    #pragma unroll
    for (int q = 0; q < 4; q++) {
        const int row = tr * 4 + q;
        #pragma unroll
        for (int j = 0; j < 8; j++) acc[q][j] += bout[cbase + tc * 8 + j];
        if (last) {
            #pragma unroll
            for (int j = 0; j < 8; j++)
                out_logits[(size_t)row * Vn + cbase + tc * 8 + j] = acc[q][j];
        }
        float m = acc[q][0];
        #pragma unroll
        for (int j = 1; j < 8; j++) m = fmaxf(m, acc[q][j]);
        for (int d = 1; d < 16; d <<= 1) m = fmaxf(m, __shfl_xor(m, d, 16));
        float s = 0.0f;
        #pragma unroll
        for (int j = 0; j < 8; j++) s += expf(acc[q][j] - m);
        for (int d = 1; d < 16; d <<= 1) s += __shfl_xor(s, d, 16);
        if (tc == 0) {
            pmax[blockIdx.x * Bn + row] = m;
            psum[blockIdx.x * Bn + row] = s;
        }
    }
}

// ---------------------------------------------------------------------------
// loss_kernel: 1 block x 256 threads. Merge 250 partials per row, compute
// target logit directly, accumulate CE into ws loss; write d_out[0] at end.
// ---------------------------------------------------------------------------
__global__ __launch_bounds__(256) void loss_kernel(
    const float* __restrict__ pmax, const float* __restrict__ psum,
    const float* __restrict__ hn, const int* __restrict__ idx,
    const float* __restrict__ Wout, const float* __restrict__ bout,
    float* __restrict__ ws_loss, float* __restrict__ out_loss,
    int step, int last)
{
    const int t = threadIdx.x;
    const int b = t >> 2, q = t & 3;

    float M = -INFINITY, S = 0.0f;
    for (int p = q; p < 250; p += 4) {
        const float m2 = pmax[p * Bn + b], s2 = psum[p * Bn + b];
        const float Mn = fmaxf(M, m2);
        S = S * expf(M - Mn) + s2 * expf(m2 - Mn);
        M = Mn;
    }
    #pragma unroll
    for (int d = 1; d < 4; d <<= 1) {
        const float m2 = __shfl_xor(M, d, 4);
        const float s2 = __shfl_xor(S, d, 4);
        const float Mn = fmaxf(M, m2);
        S = S * expf(M - Mn) + s2 * expf(m2 - Mn);
        M = Mn;
    }

    const int tgt = idx[b * Lq + step];
    const float* hb = hn + b * Hn;
    const float* wr = Wout + (size_t)tgt * Hn;
    float dot = 0.0f;
    for (int k = q * 128; k < q * 128 + 128; k += 4) {
        const float4 hv = *reinterpret_cast<const float4*>(hb + k);
        const float4 wv = *reinterpret_cast<const float4*>(wr + k);
        dot += hv.x * wv.x + hv.y * wv.y + hv.z * wv.z + hv.w * wv.w;
    }
    #pragma unroll
    for (int d = 1; d < 4; d <<= 1) dot += __shfl_xor(dot, d, 4);

    __shared__ float ce[Bn];
    if (q == 0) ce[b] = -(dot + bout[tgt] - M - logf(S));
    __syncthreads();
    if (t == 0) {
        float s = 0.0f;
        for (int i = 0; i < Bn; i++) s += ce[i];
        s *= (1.0f / Bn);
        const float acc = ws_loss[0] + s;
        ws_loss[0] = acc;
        if (last) out_loss[0] = acc;
    }
}

extern "C" void kernel_launch(void* const* d_in, const int* in_sizes, int n_in,
                              void* d_out, int out_size, void* d_ws, size_t ws_size,
                              hipStream_t stream) {
    (void)in_sizes; (void)n_in; (void)out_size; (void)ws_size;
    const int*   idx    = (const int*)  d_in[0];
    // d_in[1] hidden: unused (zeroed in forward). d_in[2] encoder_outputs: dead code.
    const float* emb    = (const float*)d_in[3];
    const float* W_attn = (const float*)d_in[4];
    const float* b_attn = (const float*)d_in[5];
    const float* W_ih   = (const float*)d_in[6];
    const float* W_hh   = (const float*)d_in[7];
    const float* b_ih   = (const float*)d_in[8];
    const float* b_hh   = (const float*)d_in[9];
    const float* W_out  = (const float*)d_in[10];
    const float* b_out  = (const float*)d_in[11];

    float* out = (float*)d_out;
    float* ws  = (float*)d_ws;
    float* hA  = ws + OFF_HA;
    float* hB  = ws + OFF_HB;
    float* Z   = ws + OFF_Z;
    float* pm  = ws + OFF_PM;
    float* psv = ws + OFF_PS;

    // d_out layout: [0] loss | attns [127][64][128] | h_fin [64][512] | logits [64][32000]
    float* out_attn   = out + 1;
    float* out_hfin   = out + 1 + (size_t)Tn * Bn * Lq;
    float* out_logits = out + 1 + (size_t)Tn * Bn * Lq + (size_t)Bn * Hn;

    init_kernel<<<dim3(128), dim3(256), 0, stream>>>(ws);

    float* hc = hA;
    float* hx = hB;
    for (int i = 0; i < Tn; i++) {
        const int last = (i == Tn - 1) ? 1 : 0;
        z_kernel<<<dim3(25), dim3(256), 0, stream>>>(
            hc, idx, emb, W_attn, b_attn, W_ih, b_ih, W_hh, b_hh, Z, i);
        gates_softmax_kernel<<<dim3(64), dim3(128), 0, stream>>>(
            Z, hc, hx, out_attn, out_hfin, i, last);
        logits_kernel<<<dim3(250), dim3(256), 0, stream>>>(
            hx, W_out, b_out, pm, psv, out_logits, last);
        loss_kernel<<<dim3(1), dim3(256), 0, stream>>>(
            pm, psv, hx, idx, W_out, b_out, ws + OFF_LOSS, out, i, last);
        float* tmp = hc; hc = hx; hx = tmp;
    }
}

// Round 2
// 15134.697 us; speedup vs baseline: 1.6060x; 1.6060x over previous
//
#include <hip/hip_runtime.h>
#include <math.h>

// Problem constants (from reference)
#define Bn 64      // batch
#define Lq 128     // output_length (= attn logits width)
#define En 512     // emb dim
#define Hn 512     // hidden
#define Vn 32000   // vocab
#define Tn 127     // steps = L-1

// Z layout per step: [Bn][3200]
//   cols [0,128)    : attn logits (incl. b_attn)
//   cols [128,1664) : gh = h @ W_hh.T + b_hh   (r: +0, z: +512, n: +1024)
//   cols [1664,3200): gi = x @ W_ih.T + b_ih
#define ZC 3200

// ws layout (float offsets)
#define OFF_LOSS 0
#define OFF_HA   64
#define OFF_HB   (OFF_HA + Bn*Hn)            // 32832
#define OFF_Z    (OFF_HB + Bn*Hn)            // 65600
#define OFF_PM   (OFF_Z + Bn*ZC)             // 270400 : pmax[250][64]
#define OFF_PS   (OFF_PM + 250*Bn)           // 286400 : psum[250][64]
#define OFF_HBF  (OFF_PS + 250*Bn)           // 302400 : h bf16 [64][512] (as ushort)

// LDS strides (floats) for fp32 z_kernel staging
#define PA 68
#define PW 132

typedef __attribute__((ext_vector_type(8))) short short8v;  // 8 bf16 (4 VGPRs)
typedef __attribute__((ext_vector_type(4))) float f32x4;

__device__ __forceinline__ unsigned short f2bf(float f) {
    unsigned u = __builtin_bit_cast(unsigned, f);
    u += 0x7fffu + ((u >> 16) & 1u);          // RNE
    return (unsigned short)(u >> 16);
}

__device__ __forceinline__ short8v pack8(float4 a, float4 b) {
    short8v r;
    r[0] = (short)f2bf(a.x); r[1] = (short)f2bf(a.y);
    r[2] = (short)f2bf(a.z); r[3] = (short)f2bf(a.w);
    r[4] = (short)f2bf(b.x); r[5] = (short)f2bf(b.y);
    r[6] = (short)f2bf(b.z); r[7] = (short)f2bf(b.w);
    return r;
}

__global__ void init_kernel(float* __restrict__ ws) {
    int i = blockIdx.x * 256 + threadIdx.x;
    if (i < Bn * Hn) ws[OFF_HA + i] = 0.0f;
    if (i == 0) ws[OFF_LOSS] = 0.0f;
}

// ---------------------------------------------------------------------------
// loss merge body: merge 250 (max,sumexp) partials per row, target logit via
// fp32 dot, accumulate CE into ws loss. 256 threads.
// ---------------------------------------------------------------------------
__device__ void loss_body(const float* __restrict__ pmax, const float* __restrict__ psum,
                          const float* __restrict__ hn, const int* __restrict__ idx,
                          const float* __restrict__ Wout, const float* __restrict__ bout,
                          float* __restrict__ ws_loss, float* __restrict__ out_loss,
                          int step, int last, float* ce /* shared [Bn] */)
{
    const int t = threadIdx.x;
    const int b = t >> 2, q = t & 3;

    float M = -INFINITY, S = 0.0f;
    for (int p = q; p < 250; p += 4) {
        const float m2 = pmax[p * Bn + b], s2 = psum[p * Bn + b];
        const float Mn = fmaxf(M, m2);
        S = S * expf(M - Mn) + s2 * expf(m2 - Mn);
        M = Mn;
    }
    #pragma unroll
    for (int d = 1; d < 4; d <<= 1) {
        const float m2 = __shfl_xor(M, d, 4);
        const float s2 = __shfl_xor(S, d, 4);
        const float Mn = fmaxf(M, m2);
        S = S * expf(M - Mn) + s2 * expf(m2 - Mn);
        M = Mn;
    }

    const int tgt = idx[b * Lq + step];
    const float* hb = hn + b * Hn;
    const float* wr = Wout + (size_t)tgt * Hn;
    float dot = 0.0f;
    for (int k = q * 128; k < q * 128 + 128; k += 4) {
        const float4 hv = *reinterpret_cast<const float4*>(hb + k);
        const float4 wv = *reinterpret_cast<const float4*>(wr + k);
        dot += hv.x * wv.x + hv.y * wv.y + hv.z * wv.z + hv.w * wv.w;
    }
    #pragma unroll
    for (int d = 1; d < 4; d <<= 1) dot += __shfl_xor(dot, d, 4);

    if (q == 0) ce[b] = -(dot + bout[tgt] - M - logf(S));
    __syncthreads();
    if (t == 0) {
        float s = 0.0f;
        for (int i = 0; i < Bn; i++) s += ce[i];
        s *= (1.0f / Bn);
        const float acc = ws_loss[0] + s;
        ws_loss[0] = acc;
        if (last) out_loss[0] = acc;
    }
}

// ---------------------------------------------------------------------------
// z_kernel: 26 blocks x 256 threads. Blocks 0..24: fp32 GEMM tiles for
// attn logits / gh / gi (unchanged). Block 25: loss merge for step-1
// (hides loss latency under this launch).
// ---------------------------------------------------------------------------
__global__ __launch_bounds__(256) void z_kernel(
    const float* __restrict__ h,      // [64][512] current hidden (= hn of step-1)
    const int*   __restrict__ idx,    // [64][128]
    const float* __restrict__ emb,    // [32000][512]
    const float* __restrict__ W_attn, const float* __restrict__ b_attn,
    const float* __restrict__ W_ih,   const float* __restrict__ b_ih,
    const float* __restrict__ W_hh,   const float* __restrict__ b_hh,
    float* __restrict__ Z, int step,
    const float* __restrict__ pmax, const float* __restrict__ psum,
    const float* __restrict__ Wout, const float* __restrict__ bout,
    float* __restrict__ ws_loss)
{
    __shared__ float As[32 * PA];   // [kk][row]
    __shared__ float Ws[32 * PW];   // [kk][col]
    __shared__ float ce[Bn];

    const int t  = threadIdx.x;
    const int blk = blockIdx.x;

    if (blk == 25) {
        if (step > 0)
            loss_body(pmax, psum, h, idx, Wout, bout, ws_loss, (float*)0, step - 1, 0, ce);
        return;
    }

    const int tr = t >> 4, tc = t & 15;

    int group, cbase, K, zbase;
    const float* Wb; const float* bias;
    if (blk == 0)       { group = 0; cbase = 0;              K = 1024; Wb = W_attn; bias = b_attn; zbase = 0; }
    else if (blk <= 12) { group = 1; cbase = (blk - 1) * 128; K = 512; Wb = W_hh;   bias = b_hh;   zbase = 128; }
    else                { group = 2; cbase = (blk - 13) * 128; K = 512; Wb = W_ih;  bias = b_ih;   zbase = 1664; }

    float acc[4][8];
    #pragma unroll
    for (int q = 0; q < 4; q++)
        #pragma unroll
        for (int j = 0; j < 8; j++) acc[q][j] = 0.0f;

    const int jprev = (step > 0) ? (step - 1) : 0;
    const int ab = t & 63, kq = t >> 6;   // A staging: row ab, k-quarter kq
    const int wc = t >> 1, wh = t & 1;    // W staging: col wc, k-half wh

    for (int k0 = 0; k0 < K; k0 += 32) {
        {
            const int kb = k0 + kq * 8;
            const float* ap;
            if (group == 0) {
                if (kb < 512) ap = emb + (size_t)idx[ab * Lq + jprev] * En + kb;
                else          ap = h + ab * Hn + (kb - 512);
            } else if (group == 1) {
                ap = h + ab * Hn + kb;
            } else {
                ap = emb + (size_t)idx[ab * Lq + step] * En + kb;
            }
            const float4 v0 = *reinterpret_cast<const float4*>(ap);
            const float4 v1 = *reinterpret_cast<const float4*>(ap + 4);
            const int kk = kq * 8;
            As[(kk + 0) * PA + ab] = v0.x;  As[(kk + 1) * PA + ab] = v0.y;
            As[(kk + 2) * PA + ab] = v0.z;  As[(kk + 3) * PA + ab] = v0.w;
            As[(kk + 4) * PA + ab] = v1.x;  As[(kk + 5) * PA + ab] = v1.y;
            As[(kk + 6) * PA + ab] = v1.z;  As[(kk + 7) * PA + ab] = v1.w;
        }
        {
            const float* wp = Wb + (size_t)(cbase + wc) * K + k0 + wh * 16;
            const float4 w0 = reinterpret_cast<const float4*>(wp)[0];
            const float4 w1 = reinterpret_cast<const float4*>(wp)[1];
            const float4 w2 = reinterpret_cast<const float4*>(wp)[2];
            const float4 w3 = reinterpret_cast<const float4*>(wp)[3];
            const int kk = wh * 16;
            Ws[(kk + 0 ) * PW + wc] = w0.x; Ws[(kk + 1 ) * PW + wc] = w0.y;
            Ws[(kk + 2 ) * PW + wc] = w0.z; Ws[(kk + 3 ) * PW + wc] = w0.w;
            Ws[(kk + 4 ) * PW + wc] = w1.x; Ws[(kk + 5 ) * PW + wc] = w1.y;
            Ws[(kk + 6 ) * PW + wc] = w1.z; Ws[(kk + 7 ) * PW + wc] = w1.w;
            Ws[(kk + 8 ) * PW + wc] = w2.x; Ws[(kk + 9 ) * PW + wc] = w2.y;
            Ws[(kk + 10) * PW + wc] = w2.z; Ws[(kk + 11) * PW + wc] = w2.w;
            Ws[(kk + 12) * PW + wc] = w3.x; Ws[(kk + 13) * PW + wc] = w3.y;
            Ws[(kk + 14) * PW + wc] = w3.z; Ws[(kk + 15) * PW + wc] = w3.w;
        }
        __syncthreads();
        #pragma unroll 4
        for (int kk = 0; kk < 32; kk++) {
            const float4 av = *reinterpret_cast<const float4*>(&As[kk * PA + tr * 4]);
            const float4 w0 = *reinterpret_cast<const float4*>(&Ws[kk * PW + tc * 8]);
            const float4 w1 = *reinterpret_cast<const float4*>(&Ws[kk * PW + tc * 8 + 4]);
            const float a0 = av.x, a1 = av.y, a2 = av.z, a3 = av.w;
            const float w[8] = {w0.x, w0.y, w0.z, w0.w, w1.x, w1.y, w1.z, w1.w};
            #pragma unroll
            for (int j = 0; j < 8; j++) {
                acc[0][j] = fmaf(a0, w[j], acc[0][j]);
                acc[1][j] = fmaf(a1, w[j], acc[1][j]);
                acc[2][j] = fmaf(a2, w[j], acc[2][j]);
                acc[3][j] = fmaf(a3, w[j], acc[3][j]);
            }
        }
        __syncthreads();
    }

    #pragma unroll
    for (int q = 0; q < 4; q++) {
        const int row = tr * 4 + q;
        #pragma unroll
        for (int j = 0; j < 8; j++) {
            const int lc = tc * 8 + j;
            Z[row * ZC + zbase + cbase + lc] = acc[q][j] + bias[cbase + lc];
        }
    }
}

// ---------------------------------------------------------------------------
// gates_softmax_kernel: 64 blocks x 128 threads. Softmax -> attns; GRU gates
// -> h_new (fp32 for recurrence + bf16 copy for the MFMA logits kernel).
// ---------------------------------------------------------------------------
__global__ __launch_bounds__(128) void gates_softmax_kernel(
    const float* __restrict__ Z, const float* __restrict__ h,
    float* __restrict__ hn, unsigned short* __restrict__ hb16,
    float* __restrict__ out_attn, float* __restrict__ out_hfin,
    int step, int last)
{
    const int b = blockIdx.x;
    const int t = threadIdx.x;
    __shared__ float red[128];

    const float x = Z[b * ZC + t];
    red[t] = x; __syncthreads();
    for (int s = 64; s > 0; s >>= 1) {
        if (t < s) red[t] = fmaxf(red[t], red[t + s]);
        __syncthreads();
    }
    const float M = red[0];
    __syncthreads();
    const float e = expf(x - M);
    red[t] = e; __syncthreads();
    for (int s = 64; s > 0; s >>= 1) {
        if (t < s) red[t] += red[t + s];
        __syncthreads();
    }
    const float S = red[0];
    out_attn[((size_t)step * Bn + b) * Lq + t] = e / S;

    #pragma unroll
    for (int q = 0; q < 4; q++) {
        const int u = t + q * 128;
        const float ghr = Z[b * ZC + 128  + u];
        const float ghz = Z[b * ZC + 640  + u];
        const float ghn = Z[b * ZC + 1152 + u];
        const float gir = Z[b * ZC + 1664 + u];
        const float giz = Z[b * ZC + 2176 + u];
        const float gin = Z[b * ZC + 2688 + u];
        const float r  = 1.0f / (1.0f + expf(-(gir + ghr)));
        const float zg = 1.0f / (1.0f + expf(-(giz + ghz)));
        const float n  = tanhf(gin + r * ghn);
        const float hv = h[b * Hn + u];
        const float hnew = (1.0f - zg) * n + zg * hv;
        hn[b * Hn + u] = hnew;
        hb16[b * Hn + u] = f2bf(hnew);
        if (last) out_hfin[b * Hn + u] = hnew;
    }
}

// ---------------------------------------------------------------------------
// logits_mfma_kernel: 250 blocks x 256 threads (4 waves). Block tile
// 64 x 128; wave w owns 32-col strip, all 64 rows. No LDS for operands:
// A (h bf16, L2-hot) loaded straight into fragments; W streamed fp32 from
// L3 and converted in-register. mfma_f32_16x16x32_bf16, fp32 accumulate.
// Epilogue: bias, optional logits store, per-block (rowmax, sumexp).
// ---------------------------------------------------------------------------
__global__ __launch_bounds__(256) void logits_mfma_kernel(
    const unsigned short* __restrict__ hb16,  // [64][512] bf16
    const float* __restrict__ Wout, const float* __restrict__ bout,
    float* __restrict__ pmax, float* __restrict__ psum,
    float* __restrict__ out_logits, int last)
{
    const int t  = threadIdx.x;
    const int w  = t >> 6;        // wave 0..3
    const int l  = t & 63;
    const int lr = l & 15;        // A-row / B-col within 16-tile
    const int lg = l >> 4;        // k-group (8 contiguous k per fragment)
    const int cb = blockIdx.x * 128 + w * 32;

    f32x4 acc[4][2];
    #pragma unroll
    for (int rt = 0; rt < 4; rt++)
        #pragma unroll
        for (int ct = 0; ct < 2; ct++)
            acc[rt][ct] = (f32x4){0.f, 0.f, 0.f, 0.f};

    const unsigned short* aptr = hb16 + lr * Hn + lg * 8;
    const float* bptr0 = Wout + (size_t)(cb + lr) * Hn + lg * 8;
    const float* bptr1 = bptr0 + 16 * Hn;

    #pragma unroll 2
    for (int ks = 0; ks < 16; ks++) {
        const int k0 = ks * 32;
        short8v a[4];
        #pragma unroll
        for (int rt = 0; rt < 4; rt++)
            a[rt] = *reinterpret_cast<const short8v*>(aptr + rt * (16 * Hn) + k0);

        const float4 x0 = *reinterpret_cast<const float4*>(bptr0 + k0);
        const float4 x1 = *reinterpret_cast<const float4*>(bptr0 + k0 + 4);
        const float4 y0 = *reinterpret_cast<const float4*>(bptr1 + k0);
        const float4 y1 = *reinterpret_cast<const float4*>(bptr1 + k0 + 4);
        short8v b0 = pack8(x0, x1);
        short8v b1 = pack8(y0, y1);

        #pragma unroll
        for (int rt = 0; rt < 4; rt++) {
            acc[rt][0] = __builtin_amdgcn_mfma_f32_16x16x32_bf16(a[rt], b0, acc[rt][0], 0, 0, 0);
            acc[rt][1] = __builtin_amdgcn_mfma_f32_16x16x32_bf16(a[rt], b1, acc[rt][1], 0, 0, 0);
        }
    }

    // Epilogue: bias + (last) store + per-row (max, sumexp) over this block's 128 cols
    __shared__ float sm[4][Bn];
    __shared__ float ss[4][Bn];

    const float bia0 = bout[cb + lr];
    const float bia1 = bout[cb + 16 + lr];

    #pragma unroll
    for (int rt = 0; rt < 4; rt++) {
        #pragma unroll
        for (int i = 0; i < 4; i++) {
            const int row = rt * 16 + lg * 4 + i;
            float v0 = acc[rt][0][i] + bia0;
            float v1 = acc[rt][1][i] + bia1;
            if (last) {
                out_logits[(size_t)row * Vn + cb + lr]      = v0;
                out_logits[(size_t)row * Vn + cb + 16 + lr] = v1;
            }
            float m = fmaxf(v0, v1);
            #pragma unroll
            for (int d = 1; d < 16; d <<= 1) m = fmaxf(m, __shfl_xor(m, d));
            float s = expf(v0 - m) + expf(v1 - m);
            #pragma unroll
            for (int d = 1; d < 16; d <<= 1) s += __shfl_xor(s, d);
            if (lr == 0) { sm[w][row] = m; ss[w][row] = s; }
        }
    }
    __syncthreads();
    if (t < Bn) {
        float M = sm[0][t], S = ss[0][t];
        #pragma unroll
        for (int ww = 1; ww < 4; ww++) {
            const float m2 = sm[ww][t], s2 = ss[ww][t];
            const float Mn = fmaxf(M, m2);
            S = S * expf(M - Mn) + s2 * expf(m2 - Mn);
            M = Mn;
        }
        pmax[blockIdx.x * Bn + t] = M;
        psum[blockIdx.x * Bn + t] = S;
    }
}

// Standalone loss for the final step (step 126).
__global__ __launch_bounds__(256) void loss_kernel(
    const float* __restrict__ pmax, const float* __restrict__ psum,
    const float* __restrict__ hn, const int* __restrict__ idx,
    const float* __restrict__ Wout, const float* __restrict__ bout,
    float* __restrict__ ws_loss, float* __restrict__ out_loss,
    int step, int last)
{
    __shared__ float ce[Bn];
    loss_body(pmax, psum, hn, idx, Wout, bout, ws_loss, out_loss, step, last, ce);
}

extern "C" void kernel_launch(void* const* d_in, const int* in_sizes, int n_in,
                              void* d_out, int out_size, void* d_ws, size_t ws_size,
                              hipStream_t stream) {
    (void)in_sizes; (void)n_in; (void)out_size; (void)ws_size;
    const int*   idx    = (const int*)  d_in[0];
    // d_in[1] hidden: unused (zeroed). d_in[2] encoder_outputs: dead code.
    const float* emb    = (const float*)d_in[3];
    const float* W_attn = (const float*)d_in[4];
    const float* b_attn = (const float*)d_in[5];
    const float* W_ih   = (const float*)d_in[6];
    const float* W_hh   = (const float*)d_in[7];
    const float* b_ih   = (const float*)d_in[8];
    const float* b_hh   = (const float*)d_in[9];
    const float* W_out  = (const float*)d_in[10];
    const float* b_out  = (const float*)d_in[11];

    float* out = (float*)d_out;
    float* ws  = (float*)d_ws;
    float* hA  = ws + OFF_HA;
    float* hB  = ws + OFF_HB;
    float* Z   = ws + OFF_Z;
    float* pm  = ws + OFF_PM;
    float* psv = ws + OFF_PS;
    unsigned short* hb16 = (unsigned short*)(ws + OFF_HBF);

    // d_out layout: [0] loss | attns [127][64][128] | h_fin [64][512] | logits [64][32000]
    float* out_attn   = out + 1;
    float* out_hfin   = out + 1 + (size_t)Tn * Bn * Lq;
    float* out_logits = out + 1 + (size_t)Tn * Bn * Lq + (size_t)Bn * Hn;

    init_kernel<<<dim3(128), dim3(256), 0, stream>>>(ws);

    float* hc = hA;
    float* hx = hB;
    for (int i = 0; i < Tn; i++) {
        const int last = (i == Tn - 1) ? 1 : 0;
        // blocks 0..24: Z GEMMs; block 25: loss merge for step i-1 (pm/ps from
        // the previous logits launch, h = hc = h_new of step i-1)
        z_kernel<<<dim3(26), dim3(256), 0, stream>>>(
            hc, idx, emb, W_attn, b_attn, W_ih, b_ih, W_hh, b_hh, Z, i,
            pm, psv, W_out, b_out, ws + OFF_LOSS);
        gates_softmax_kernel<<<dim3(64), dim3(128), 0, stream>>>(
            Z, hc, hx, hb16, out_attn, out_hfin, i, last);
        logits_mfma_kernel<<<dim3(250), dim3(256), 0, stream>>>(
            hb16, W_out, b_out, pm, psv, out_logits, last);
        float* tmp = hc; hc = hx; hx = tmp;
    }
    // final loss merge for step 126 (hc now = final h)
    loss_kernel<<<dim3(1), dim3(256), 0, stream>>>(
        pm, psv, hc, idx, W_out, b_out, ws + OFF_LOSS, out, Tn - 1, 1);
}

// Round 3
// 5904.719 us; speedup vs baseline: 4.1163x; 2.5632x over previous
//
#include <hip/hip_runtime.h>
#include <math.h>

// Problem constants (from reference)
#define Bn 64      // batch
#define Lq 128     // output_length
#define En 512     // emb dim
#define Hn 512     // hidden
#define Vn 32000   // vocab
#define Tn 127     // steps = L-1

typedef __attribute__((ext_vector_type(8))) short short8v;  // 8 bf16 (4 VGPRs)
typedef __attribute__((ext_vector_type(4))) float f32x4;
typedef unsigned short ushort_t;

__device__ __forceinline__ ushort_t f2bf(float f) {
    unsigned u = __builtin_bit_cast(unsigned, f);
    u += 0x7fffu + ((u >> 16) & 1u);          // RNE
    return (ushort_t)(u >> 16);
}
__device__ __forceinline__ float bf2f(ushort_t h) {
    return __builtin_bit_cast(float, ((unsigned)h) << 16);
}
__device__ __forceinline__ short8v pack8(float4 a, float4 b) {
    short8v r;
    r[0] = (short)f2bf(a.x); r[1] = (short)f2bf(a.y);
    r[2] = (short)f2bf(a.z); r[3] = (short)f2bf(a.w);
    r[4] = (short)f2bf(b.x); r[5] = (short)f2bf(b.y);
    r[6] = (short)f2bf(b.z); r[7] = (short)f2bf(b.w);
    return r;
}

// ---------------------------------------------------------------------------
// shared loss merge body: merge 250 (max,sumexp) partials per row, target
// logit via fp32 dot, accumulate CE. 256 threads.
// ---------------------------------------------------------------------------
__device__ void loss_body(const float* __restrict__ pmax, const float* __restrict__ psum,
                          const float* __restrict__ hn, const int* __restrict__ idx,
                          const float* __restrict__ Wout, const float* __restrict__ bout,
                          float* __restrict__ ws_loss, float* __restrict__ out_loss,
                          int step, int last, float* ce /* shared [Bn] */)
{
    const int t = threadIdx.x;
    const int b = t >> 2, q = t & 3;

    float M = -INFINITY, S = 0.0f;
    for (int p = q; p < 250; p += 4) {
        const float m2 = pmax[p * Bn + b], s2 = psum[p * Bn + b];
        const float Mn = fmaxf(M, m2);
        S = S * expf(M - Mn) + s2 * expf(m2 - Mn);
        M = Mn;
    }
    #pragma unroll
    for (int d = 1; d < 4; d <<= 1) {
        const float m2 = __shfl_xor(M, d, 4);
        const float s2 = __shfl_xor(S, d, 4);
        const float Mn = fmaxf(M, m2);
        S = S * expf(M - Mn) + s2 * expf(m2 - Mn);
        M = Mn;
    }

    const int tgt = idx[b * Lq + step];
    const float* hb = hn + b * Hn;
    const float* wr = Wout + (size_t)tgt * Hn;
    float dot = 0.0f;
    for (int k = q * 128; k < q * 128 + 128; k += 4) {
        const float4 hv = *reinterpret_cast<const float4*>(hb + k);
        const float4 wv = *reinterpret_cast<const float4*>(wr + k);
        dot += hv.x * wv.x + hv.y * wv.y + hv.z * wv.z + hv.w * wv.w;
    }
    #pragma unroll
    for (int d = 1; d < 4; d <<= 1) dot += __shfl_xor(dot, d, 4);

    if (q == 0) ce[b] = -(dot + bout[tgt] - M - logf(S));
    __syncthreads();
    if (t == 0) {
        float s = 0.0f;
        for (int i = 0; i < Bn; i++) s += ce[i];
        s *= (1.0f / Bn);
        const float acc = ws_loss[0] + s;
        ws_loss[0] = acc;
        if (last) out_loss[0] = acc;
    }
}

// ===========================================================================
// ============================ FAST PATH ====================================
// ===========================================================================

// ws byte offsets (fast path)
constexpr size_t FP_LOSS  = 0;
constexpr size_t FP_HF0   = 64;                      // fp32 h buf 0 [64][512]
constexpr size_t FP_HF1   = FP_HF0   + 131072;
constexpr size_t FP_HHI0  = FP_HF1   + 131072;       // bf16 h hi/lo, 2 bufs
constexpr size_t FP_HLO0  = FP_HHI0  + 65536;
constexpr size_t FP_HHI1  = FP_HLO0  + 65536;
constexpr size_t FP_HLO1  = FP_HHI1  + 65536;
constexpr size_t FP_ZH    = FP_HLO1  + 65536;        // fp32 [64][1664]
constexpr size_t FP_PM    = FP_ZH    + 425984;       // fp32 [2][250][64]
constexpr size_t FP_PS    = FP_PM    + 128000;
constexpr size_t FP_WHHHI = FP_PS    + 128000;       // bf16 [1536][512]
constexpr size_t FP_WHHLO = FP_WHHHI + 1572864;
constexpr size_t FP_WAHHI = FP_WHHLO + 1572864;      // bf16 [128][512]
constexpr size_t FP_WAHLO = FP_WAHHI + 131072;
constexpr size_t FP_WO16  = FP_WAHLO + 131072;       // bf16 [32000][512]
constexpr size_t FP_GI    = FP_WO16  + 32768000;     // fp32 [127][64][1536]
constexpr size_t FP_GAX   = FP_GI    + 49938432;     // fp32 [127][64][128]
constexpr size_t FP_END   = FP_GAX   + 4161536;      // 91,482,176 B

// zero h0, zh, loss
__global__ __launch_bounds__(256) void zero_ws_kernel(
    float* __restrict__ h0, float* __restrict__ zh, float* __restrict__ loss)
{
    const int i = blockIdx.x * 256 + threadIdx.x;
    if (i < Bn * Hn) h0[i] = 0.0f;
    else if (i < Bn * Hn + Bn * 1664) zh[i - Bn * Hn] = 0.0f;
    else if (i == Bn * Hn + Bn * 1664) loss[0] = 0.0f;
}

// split W_hh and W_attn[:,512:] into bf16 hi/lo tables
__global__ __launch_bounds__(256) void split_w_kernel(
    const float* __restrict__ Whh, const float* __restrict__ Wattn,
    ushort_t* __restrict__ whhhi, ushort_t* __restrict__ whhlo,
    ushort_t* __restrict__ wahhi, ushort_t* __restrict__ wahlo)
{
    const int i = blockIdx.x * 256 + threadIdx.x;
    const int N1 = 1536 * 512;
    if (i < N1) {
        const float w = Whh[i];
        const ushort_t hi = f2bf(w);
        whhhi[i] = hi;
        whhlo[i] = f2bf(w - bf2f(hi));
    } else if (i < N1 + 128 * 512) {
        const int e = i - N1;
        const int r = e >> 9, k = e & 511;
        const float w = Wattn[r * 1024 + 512 + k];
        const ushort_t hi = f2bf(w);
        wahhi[e] = hi;
        wahlo[e] = f2bf(w - bf2f(hi));
    }
}

// W_out -> bf16 (grid-stride)
__global__ __launch_bounds__(256) void wout_cvt_kernel(
    const float* __restrict__ Wout, ushort_t* __restrict__ wo16)
{
    const size_t N = (size_t)Vn * Hn;
    for (size_t i = blockIdx.x * 256 + threadIdx.x; i < N; i += (size_t)gridDim.x * 256)
        wo16[i] = f2bf(Wout[i]);
}

// Precompute recurrence-free GEMMs: out[t][64][cols] = emb[idx[:,t]] @ Wb[:, :512].T + bias
// grid = 127 * ncb blocks, 256 threads, fp32 VALU (one-time cost).
#define PA 68
#define PW 132
__global__ __launch_bounds__(256) void pre_gemm_kernel(
    const int* __restrict__ idx, const float* __restrict__ emb,
    const float* __restrict__ Wb, int ldw, const float* __restrict__ bias,
    float* __restrict__ outp, int ldo, int ncb)
{
    const int blk = blockIdx.x;
    const int ts  = blk / ncb;
    const int cbase = (blk % ncb) * 128;
    const int t  = threadIdx.x;
    const int tr = t >> 4, tc = t & 15;

    __shared__ float As[32 * PA];
    __shared__ float Ws[32 * PW];

    float acc[4][8];
    #pragma unroll
    for (int q = 0; q < 4; q++)
        #pragma unroll
        for (int j = 0; j < 8; j++) acc[q][j] = 0.0f;

    const int ab = t & 63, kq = t >> 6;
    const int wc = t >> 1, wh = t & 1;

    for (int k0 = 0; k0 < 512; k0 += 32) {
        {
            const float* ap = emb + (size_t)idx[ab * Lq + ts] * En + k0 + kq * 8;
            const float4 v0 = *reinterpret_cast<const float4*>(ap);
            const float4 v1 = *reinterpret_cast<const float4*>(ap + 4);
            const int kk = kq * 8;
            As[(kk + 0) * PA + ab] = v0.x;  As[(kk + 1) * PA + ab] = v0.y;
            As[(kk + 2) * PA + ab] = v0.z;  As[(kk + 3) * PA + ab] = v0.w;
            As[(kk + 4) * PA + ab] = v1.x;  As[(kk + 5) * PA + ab] = v1.y;
            As[(kk + 6) * PA + ab] = v1.z;  As[(kk + 7) * PA + ab] = v1.w;
        }
        {
            const float* wp = Wb + (size_t)(cbase + wc) * ldw + k0 + wh * 16;
            const float4 w0 = reinterpret_cast<const float4*>(wp)[0];
            const float4 w1 = reinterpret_cast<const float4*>(wp)[1];
            const float4 w2 = reinterpret_cast<const float4*>(wp)[2];
            const float4 w3 = reinterpret_cast<const float4*>(wp)[3];
            const int kk = wh * 16;
            Ws[(kk + 0 ) * PW + wc] = w0.x; Ws[(kk + 1 ) * PW + wc] = w0.y;
            Ws[(kk + 2 ) * PW + wc] = w0.z; Ws[(kk + 3 ) * PW + wc] = w0.w;
            Ws[(kk + 4 ) * PW + wc] = w1.x; Ws[(kk + 5 ) * PW + wc] = w1.y;
            Ws[(kk + 6 ) * PW + wc] = w1.z; Ws[(kk + 7 ) * PW + wc] = w1.w;
            Ws[(kk + 8 ) * PW + wc] = w2.x; Ws[(kk + 9 ) * PW + wc] = w2.y;
            Ws[(kk + 10) * PW + wc] = w2.z; Ws[(kk + 11) * PW + wc] = w2.w;
            Ws[(kk + 12) * PW + wc] = w3.x; Ws[(kk + 13) * PW + wc] = w3.y;
            Ws[(kk + 14) * PW + wc] = w3.z; Ws[(kk + 15) * PW + wc] = w3.w;
        }
        __syncthreads();
        #pragma unroll 4
        for (int kk = 0; kk < 32; kk++) {
            const float4 av = *reinterpret_cast<const float4*>(&As[kk * PA + tr * 4]);
            const float4 w0 = *reinterpret_cast<const float4*>(&Ws[kk * PW + tc * 8]);
            const float4 w1 = *reinterpret_cast<const float4*>(&Ws[kk * PW + tc * 8 + 4]);
            const float a0 = av.x, a1 = av.y, a2 = av.z, a3 = av.w;
            const float w[8] = {w0.x, w0.y, w0.z, w0.w, w1.x, w1.y, w1.z, w1.w};
            #pragma unroll
            for (int j = 0; j < 8; j++) {
                acc[0][j] = fmaf(a0, w[j], acc[0][j]);
                acc[1][j] = fmaf(a1, w[j], acc[1][j]);
                acc[2][j] = fmaf(a2, w[j], acc[2][j]);
                acc[3][j] = fmaf(a3, w[j], acc[3][j]);
            }
        }
        __syncthreads();
    }

    #pragma unroll
    for (int q = 0; q < 4; q++) {
        const int row = tr * 4 + q;
        #pragma unroll
        for (int j = 0; j < 8; j++) {
            const int lc = tc * 8 + j;
            outp[((size_t)ts * 64 + row) * ldo + cbase + lc] = acc[q][j] + bias[cbase + lc];
        }
    }
}

// ---------------------------------------------------------------------------
// fused_step_kernel: grid 264.
//   blocks 0..249 : logits tile (bf16 MFMA, W_out bf16 pre-converted),
//                   per-block (rowmax,sumexp) into pm/ps[step&1].
//   blocks 250..262: zh = h @ [W_ah | W_hh].T via 3-term bf16 hi/lo split MFMA.
//   block 263     : loss merge for step-1 (pm/ps[(step&1)^1], prev fp32 h).
// ---------------------------------------------------------------------------
__global__ __launch_bounds__(256) void fused_step_kernel(
    const ushort_t* __restrict__ curhi, const ushort_t* __restrict__ curlo,
    const float* __restrict__ prevh, const int* __restrict__ idx,
    const ushort_t* __restrict__ wo16, const float* __restrict__ WoutF,
    const float* __restrict__ bout,
    const ushort_t* __restrict__ whhhi, const ushort_t* __restrict__ whhlo,
    const ushort_t* __restrict__ wahhi, const ushort_t* __restrict__ wahlo,
    float* __restrict__ zh,
    float* __restrict__ pmA, float* __restrict__ psA,
    float* __restrict__ out_logits, float* __restrict__ ws_loss,
    int step, int last)
{
    __shared__ float sm[4][Bn];
    __shared__ float ss[4][Bn];
    __shared__ float ce[Bn];

    const int t   = threadIdx.x;
    const int blk = blockIdx.x;
    const int par = step & 1;

    if (blk < 250) {
        // ---------------- logits ----------------
        const int w  = t >> 6, l = t & 63;
        const int lr = l & 15, lg = l >> 4;
        const int cb = blk * 128 + w * 32;

        f32x4 acc[4][2];
        #pragma unroll
        for (int rt = 0; rt < 4; rt++)
            #pragma unroll
            for (int ct = 0; ct < 2; ct++)
                acc[rt][ct] = (f32x4){0.f, 0.f, 0.f, 0.f};

        const ushort_t* aptr  = curhi + lr * Hn + lg * 8;
        const ushort_t* bptr0 = wo16 + (size_t)(cb + lr) * Hn + lg * 8;
        const ushort_t* bptr1 = bptr0 + 16 * Hn;

        #pragma unroll 2
        for (int ks = 0; ks < 16; ks++) {
            const int k0 = ks * 32;
            short8v a[4];
            #pragma unroll
            for (int rt = 0; rt < 4; rt++)
                a[rt] = *reinterpret_cast<const short8v*>(aptr + rt * (16 * Hn) + k0);
            const short8v b0 = *reinterpret_cast<const short8v*>(bptr0 + k0);
            const short8v b1 = *reinterpret_cast<const short8v*>(bptr1 + k0);
            #pragma unroll
            for (int rt = 0; rt < 4; rt++) {
                acc[rt][0] = __builtin_amdgcn_mfma_f32_16x16x32_bf16(a[rt], b0, acc[rt][0], 0, 0, 0);
                acc[rt][1] = __builtin_amdgcn_mfma_f32_16x16x32_bf16(a[rt], b1, acc[rt][1], 0, 0, 0);
            }
        }

        float* pm = pmA + par * (250 * Bn);
        float* ps = psA + par * (250 * Bn);
        const float bia0 = bout[cb + lr];
        const float bia1 = bout[cb + 16 + lr];

        #pragma unroll
        for (int rt = 0; rt < 4; rt++) {
            #pragma unroll
            for (int i = 0; i < 4; i++) {
                const int row = rt * 16 + lg * 4 + i;
                float v0 = acc[rt][0][i] + bia0;
                float v1 = acc[rt][1][i] + bia1;
                if (last) {
                    out_logits[(size_t)row * Vn + cb + lr]      = v0;
                    out_logits[(size_t)row * Vn + cb + 16 + lr] = v1;
                }
                float m = fmaxf(v0, v1);
                #pragma unroll
                for (int d = 1; d < 16; d <<= 1) m = fmaxf(m, __shfl_xor(m, d));
                float s = expf(v0 - m) + expf(v1 - m);
                #pragma unroll
                for (int d = 1; d < 16; d <<= 1) s += __shfl_xor(s, d);
                if (lr == 0) { sm[w][row] = m; ss[w][row] = s; }
            }
        }
        __syncthreads();
        if (t < Bn) {
            float M = sm[0][t], S = ss[0][t];
            #pragma unroll
            for (int ww = 1; ww < 4; ww++) {
                const float m2 = sm[ww][t], s2 = ss[ww][t];
                const float Mn = fmaxf(M, m2);
                S = S * expf(M - Mn) + s2 * expf(m2 - Mn);
                M = Mn;
            }
            pm[blk * Bn + t] = M;
            ps[blk * Bn + t] = S;
        }
    } else if (blk < 263) {
        // ---------------- zh (3-term bf16 split MFMA) ----------------
        const int bz = blk - 250;
        const int w  = t >> 6, l = t & 63;
        const int lr = l & 15, lg = l >> 4;
        const int cb = bz * 128 + w * 32;          // col base in [0,1664)

        const ushort_t* whi; const ushort_t* wlo; int cofs;
        if (bz == 0) { whi = wahhi; wlo = wahlo; cofs = cb; }
        else         { whi = whhhi; wlo = whhlo; cofs = cb - 128; }

        f32x4 acc[4][2];
        #pragma unroll
        for (int rt = 0; rt < 4; rt++)
            #pragma unroll
            for (int ct = 0; ct < 2; ct++)
                acc[rt][ct] = (f32x4){0.f, 0.f, 0.f, 0.f};

        const ushort_t* ahip = curhi + lr * Hn + lg * 8;
        const ushort_t* alop = curlo + lr * Hn + lg * 8;
        const ushort_t* bh0  = whi + (size_t)(cofs + lr) * Hn + lg * 8;
        const ushort_t* bh1  = bh0 + 16 * Hn;
        const ushort_t* bl0  = wlo + (size_t)(cofs + lr) * Hn + lg * 8;
        const ushort_t* bl1  = bl0 + 16 * Hn;

        for (int ks = 0; ks < 16; ks++) {
            const int k0 = ks * 32;
            short8v ahi[4], alo[4];
            #pragma unroll
            for (int rt = 0; rt < 4; rt++) {
                ahi[rt] = *reinterpret_cast<const short8v*>(ahip + rt * (16 * Hn) + k0);
                alo[rt] = *reinterpret_cast<const short8v*>(alop + rt * (16 * Hn) + k0);
            }
            const short8v vh0 = *reinterpret_cast<const short8v*>(bh0 + k0);
            const short8v vh1 = *reinterpret_cast<const short8v*>(bh1 + k0);
            const short8v vl0 = *reinterpret_cast<const short8v*>(bl0 + k0);
            const short8v vl1 = *reinterpret_cast<const short8v*>(bl1 + k0);
            #pragma unroll
            for (int rt = 0; rt < 4; rt++) {
                acc[rt][0] = __builtin_amdgcn_mfma_f32_16x16x32_bf16(ahi[rt], vh0, acc[rt][0], 0, 0, 0);
                acc[rt][0] = __builtin_amdgcn_mfma_f32_16x16x32_bf16(alo[rt], vh0, acc[rt][0], 0, 0, 0);
                acc[rt][0] = __builtin_amdgcn_mfma_f32_16x16x32_bf16(ahi[rt], vl0, acc[rt][0], 0, 0, 0);
                acc[rt][1] = __builtin_amdgcn_mfma_f32_16x16x32_bf16(ahi[rt], vh1, acc[rt][1], 0, 0, 0);
                acc[rt][1] = __builtin_amdgcn_mfma_f32_16x16x32_bf16(alo[rt], vh1, acc[rt][1], 0, 0, 0);
                acc[rt][1] = __builtin_amdgcn_mfma_f32_16x16x32_bf16(ahi[rt], vl1, acc[rt][1], 0, 0, 0);
            }
        }

        #pragma unroll
        for (int rt = 0; rt < 4; rt++) {
            #pragma unroll
            for (int i = 0; i < 4; i++) {
                const int row = rt * 16 + lg * 4 + i;
                zh[row * 1664 + cb + lr]      = acc[rt][0][i];
                zh[row * 1664 + cb + 16 + lr] = acc[rt][1][i];
            }
        }
    } else {
        // ---------------- loss merge for step-1 ----------------
        if (step > 0) {
            const float* pm = pmA + (par ^ 1) * (250 * Bn);
            const float* ps = psA + (par ^ 1) * (250 * Bn);
            loss_body(pm, ps, prevh, idx, WoutF, bout, ws_loss, (float*)0, step - 1, 0, ce);
        }
    }
}

// ---------------------------------------------------------------------------
// gates2_kernel: 64 blocks x 128 threads. attn softmax (Gax + zh[:,0:128]),
// GRU gates (Gi + zh gh part + b_hh) -> h_new fp32 + bf16 hi/lo split.
// ---------------------------------------------------------------------------
__global__ __launch_bounds__(128) void gates2_kernel(
    const float* __restrict__ zh, const float* __restrict__ Gi,
    const float* __restrict__ Gax, const float* __restrict__ b_hh,
    const float* __restrict__ hin, float* __restrict__ hout,
    ushort_t* __restrict__ hhi, ushort_t* __restrict__ hlo,
    float* __restrict__ out_attn, float* __restrict__ out_hfin,
    int step, int last)
{
    const int b = blockIdx.x;
    const int t = threadIdx.x;
    __shared__ float red[128];

    const int jp = (step > 0) ? (step - 1) : 0;
    const float x = zh[b * 1664 + t] + Gax[(size_t)jp * (Bn * 128) + b * 128 + t];
    red[t] = x; __syncthreads();
    for (int s = 64; s > 0; s >>= 1) {
        if (t < s) red[t] = fmaxf(red[t], red[t + s]);
        __syncthreads();
    }
    const float M = red[0];
    __syncthreads();
    const float e = expf(x - M);
    red[t] = e; __syncthreads();
    for (int s = 64; s > 0; s >>= 1) {
        if (t < s) red[t] += red[t + s];
        __syncthreads();
    }
    const float S = red[0];
    out_attn[((size_t)step * Bn + b) * Lq + t] = e / S;

    const float* gi = Gi + (size_t)step * (Bn * 1536) + b * 1536;
    #pragma unroll
    for (int q = 0; q < 4; q++) {
        const int u = t + q * 128;
        const float gir = gi[u];
        const float giz = gi[512 + u];
        const float gin = gi[1024 + u];
        const float ghr = zh[b * 1664 + 128  + u] + b_hh[u];
        const float ghz = zh[b * 1664 + 640  + u] + b_hh[512 + u];
        const float ghn = zh[b * 1664 + 1152 + u] + b_hh[1024 + u];
        const float r  = 1.0f / (1.0f + expf(-(gir + ghr)));
        const float zg = 1.0f / (1.0f + expf(-(giz + ghz)));
        const float n  = tanhf(gin + r * ghn);
        const float hv = hin[b * Hn + u];
        const float hnew = (1.0f - zg) * n + zg * hv;
        hout[b * Hn + u] = hnew;
        const ushort_t hi = f2bf(hnew);
        hhi[b * Hn + u] = hi;
        hlo[b * Hn + u] = f2bf(hnew - bf2f(hi));
        if (last) out_hfin[b * Hn + u] = hnew;
    }
}

__global__ __launch_bounds__(256) void final_loss_kernel(
    const float* __restrict__ pmax, const float* __restrict__ psum,
    const float* __restrict__ hn, const int* __restrict__ idx,
    const float* __restrict__ Wout, const float* __restrict__ bout,
    float* __restrict__ ws_loss, float* __restrict__ out_loss)
{
    __shared__ float ce[Bn];
    loss_body(pmax, psum, hn, idx, Wout, bout, ws_loss, out_loss, Tn - 1, 1, ce);
}

// ===========================================================================
// ======================= FALLBACK (round-2 path) ===========================
// ===========================================================================
#define ZC 3200
#define OFF_LOSS 0
#define OFF_HA   64
#define OFF_HB   (OFF_HA + Bn*Hn)
#define OFF_Z    (OFF_HB + Bn*Hn)
#define OFF_PM   (OFF_Z + Bn*ZC)
#define OFF_PS   (OFF_PM + 250*Bn)
#define OFF_HBF  (OFF_PS + 250*Bn)

__global__ void init_kernel(float* __restrict__ ws) {
    int i = blockIdx.x * 256 + threadIdx.x;
    if (i < Bn * Hn) ws[OFF_HA + i] = 0.0f;
    if (i == 0) ws[OFF_LOSS] = 0.0f;
}

__global__ __launch_bounds__(256) void z_kernel(
    const float* __restrict__ h, const int* __restrict__ idx,
    const float* __restrict__ emb,
    const float* __restrict__ W_attn, const float* __restrict__ b_attn,
    const float* __restrict__ W_ih,   const float* __restrict__ b_ih,
    const float* __restrict__ W_hh,   const float* __restrict__ b_hh,
    float* __restrict__ Z, int step,
    const float* __restrict__ pmax, const float* __restrict__ psum,
    const float* __restrict__ Wout, const float* __restrict__ bout,
    float* __restrict__ ws_loss)
{
    __shared__ float As[32 * PA];
    __shared__ float Ws[32 * PW];
    __shared__ float ce[Bn];

    const int t  = threadIdx.x;
    const int blk = blockIdx.x;

    if (blk == 25) {
        if (step > 0)
            loss_body(pmax, psum, h, idx, Wout, bout, ws_loss, (float*)0, step - 1, 0, ce);
        return;
    }

    const int tr = t >> 4, tc = t & 15;
    int group, cbase, K, zbase;
    const float* Wb; const float* bias;
    if (blk == 0)       { group = 0; cbase = 0;              K = 1024; Wb = W_attn; bias = b_attn; zbase = 0; }
    else if (blk <= 12) { group = 1; cbase = (blk - 1) * 128; K = 512; Wb = W_hh;   bias = b_hh;   zbase = 128; }
    else                { group = 2; cbase = (blk - 13) * 128; K = 512; Wb = W_ih;  bias = b_ih;   zbase = 1664; }

    float acc[4][8];
    #pragma unroll
    for (int q = 0; q < 4; q++)
        #pragma unroll
        for (int j = 0; j < 8; j++) acc[q][j] = 0.0f;

    const int jprev = (step > 0) ? (step - 1) : 0;
    const int ab = t & 63, kq = t >> 6;
    const int wc = t >> 1, wh = t & 1;

    for (int k0 = 0; k0 < K; k0 += 32) {
        {
            const int kb = k0 + kq * 8;
            const float* ap;
            if (group == 0) {
                if (kb < 512) ap = emb + (size_t)idx[ab * Lq + jprev] * En + kb;
                else          ap = h + ab * Hn + (kb - 512);
            } else if (group == 1) {
                ap = h + ab * Hn + kb;
            } else {
                ap = emb + (size_t)idx[ab * Lq + step] * En + kb;
            }
            const float4 v0 = *reinterpret_cast<const float4*>(ap);
            const float4 v1 = *reinterpret_cast<const float4*>(ap + 4);
            const int kk = kq * 8;
            As[(kk + 0) * PA + ab] = v0.x;  As[(kk + 1) * PA + ab] = v0.y;
            As[(kk + 2) * PA + ab] = v0.z;  As[(kk + 3) * PA + ab] = v0.w;
            As[(kk + 4) * PA + ab] = v1.x;  As[(kk + 5) * PA + ab] = v1.y;
            As[(kk + 6) * PA + ab] = v1.z;  As[(kk + 7) * PA + ab] = v1.w;
        }
        {
            const float* wp = Wb + (size_t)(cbase + wc) * K + k0 + wh * 16;
            const float4 w0 = reinterpret_cast<const float4*>(wp)[0];
            const float4 w1 = reinterpret_cast<const float4*>(wp)[1];
            const float4 w2 = reinterpret_cast<const float4*>(wp)[2];
            const float4 w3 = reinterpret_cast<const float4*>(wp)[3];
            const int kk = wh * 16;
            Ws[(kk + 0 ) * PW + wc] = w0.x; Ws[(kk + 1 ) * PW + wc] = w0.y;
            Ws[(kk + 2 ) * PW + wc] = w0.z; Ws[(kk + 3 ) * PW + wc] = w0.w;
            Ws[(kk + 4 ) * PW + wc] = w1.x; Ws[(kk + 5 ) * PW + wc] = w1.y;
            Ws[(kk + 6 ) * PW + wc] = w1.z; Ws[(kk + 7 ) * PW + wc] = w1.w;
            Ws[(kk + 8 ) * PW + wc] = w2.x; Ws[(kk + 9 ) * PW + wc] = w2.y;
            Ws[(kk + 10) * PW + wc] = w2.z; Ws[(kk + 11) * PW + wc] = w2.w;
            Ws[(kk + 12) * PW + wc] = w3.x; Ws[(kk + 13) * PW + wc] = w3.y;
            Ws[(kk + 14) * PW + wc] = w3.z; Ws[(kk + 15) * PW + wc] = w3.w;
        }
        __syncthreads();
        #pragma unroll 4
        for (int kk = 0; kk < 32; kk++) {
            const float4 av = *reinterpret_cast<const float4*>(&As[kk * PA + tr * 4]);
            const float4 w0 = *reinterpret_cast<const float4*>(&Ws[kk * PW + tc * 8]);
            const float4 w1 = *reinterpret_cast<const float4*>(&Ws[kk * PW + tc * 8 + 4]);
            const float a0 = av.x, a1 = av.y, a2 = av.z, a3 = av.w;
            const float w[8] = {w0.x, w0.y, w0.z, w0.w, w1.x, w1.y, w1.z, w1.w};
            #pragma unroll
            for (int j = 0; j < 8; j++) {
                acc[0][j] = fmaf(a0, w[j], acc[0][j]);
                acc[1][j] = fmaf(a1, w[j], acc[1][j]);
                acc[2][j] = fmaf(a2, w[j], acc[2][j]);
                acc[3][j] = fmaf(a3, w[j], acc[3][j]);
            }
        }
        __syncthreads();
    }

    #pragma unroll
    for (int q = 0; q < 4; q++) {
        const int row = tr * 4 + q;
        #pragma unroll
        for (int j = 0; j < 8; j++) {
            const int lc = tc * 8 + j;
            Z[row * ZC + zbase + cbase + lc] = acc[q][j] + bias[cbase + lc];
        }
    }
}

__global__ __launch_bounds__(128) void gates_softmax_kernel(
    const float* __restrict__ Z, const float* __restrict__ h,
    float* __restrict__ hn, ushort_t* __restrict__ hb16,
    float* __restrict__ out_attn, float* __restrict__ out_hfin,
    int step, int last)
{
    const int b = blockIdx.x;
    const int t = threadIdx.x;
    __shared__ float red[128];

    const float x = Z[b * ZC + t];
    red[t] = x; __syncthreads();
    for (int s = 64; s > 0; s >>= 1) {
        if (t < s) red[t] = fmaxf(red[t], red[t + s]);
        __syncthreads();
    }
    const float M = red[0];
    __syncthreads();
    const float e = expf(x - M);
    red[t] = e; __syncthreads();
    for (int s = 64; s > 0; s >>= 1) {
        if (t < s) red[t] += red[t + s];
        __syncthreads();
    }
    const float S = red[0];
    out_attn[((size_t)step * Bn + b) * Lq + t] = e / S;

    #pragma unroll
    for (int q = 0; q < 4; q++) {
        const int u = t + q * 128;
        const float ghr = Z[b * ZC + 128  + u];
        const float ghz = Z[b * ZC + 640  + u];
        const float ghn = Z[b * ZC + 1152 + u];
        const float gir = Z[b * ZC + 1664 + u];
        const float giz = Z[b * ZC + 2176 + u];
        const float gin = Z[b * ZC + 2688 + u];
        const float r  = 1.0f / (1.0f + expf(-(gir + ghr)));
        const float zg = 1.0f / (1.0f + expf(-(giz + ghz)));
        const float n  = tanhf(gin + r * ghn);
        const float hv = h[b * Hn + u];
        const float hnew = (1.0f - zg) * n + zg * hv;
        hn[b * Hn + u] = hnew;
        hb16[b * Hn + u] = f2bf(hnew);
        if (last) out_hfin[b * Hn + u] = hnew;
    }
}

__global__ __launch_bounds__(256) void logits_mfma_kernel(
    const ushort_t* __restrict__ hb16,
    const float* __restrict__ Wout, const float* __restrict__ bout,
    float* __restrict__ pmax, float* __restrict__ psum,
    float* __restrict__ out_logits, int last)
{
    const int t  = threadIdx.x;
    const int w  = t >> 6;
    const int l  = t & 63;
    const int lr = l & 15;
    const int lg = l >> 4;
    const int cb = blockIdx.x * 128 + w * 32;

    f32x4 acc[4][2];
    #pragma unroll
    for (int rt = 0; rt < 4; rt++)
        #pragma unroll
        for (int ct = 0; ct < 2; ct++)
            acc[rt][ct] = (f32x4){0.f, 0.f, 0.f, 0.f};

    const ushort_t* aptr = hb16 + lr * Hn + lg * 8;
    const float* bptr0 = Wout + (size_t)(cb + lr) * Hn + lg * 8;
    const float* bptr1 = bptr0 + 16 * Hn;

    #pragma unroll 2
    for (int ks = 0; ks < 16; ks++) {
        const int k0 = ks * 32;
        short8v a[4];
        #pragma unroll
        for (int rt = 0; rt < 4; rt++)
            a[rt] = *reinterpret_cast<const short8v*>(aptr + rt * (16 * Hn) + k0);

        const float4 x0 = *reinterpret_cast<const float4*>(bptr0 + k0);
        const float4 x1 = *reinterpret_cast<const float4*>(bptr0 + k0 + 4);
        const float4 y0 = *reinterpret_cast<const float4*>(bptr1 + k0);
        const float4 y1 = *reinterpret_cast<const float4*>(bptr1 + k0 + 4);
        short8v b0 = pack8(x0, x1);
        short8v b1 = pack8(y0, y1);

        #pragma unroll
        for (int rt = 0; rt < 4; rt++) {
            acc[rt][0] = __builtin_amdgcn_mfma_f32_16x16x32_bf16(a[rt], b0, acc[rt][0], 0, 0, 0);
            acc[rt][1] = __builtin_amdgcn_mfma_f32_16x16x32_bf16(a[rt], b1, acc[rt][1], 0, 0, 0);
        }
    }

    __shared__ float sm[4][Bn];
    __shared__ float ss[4][Bn];

    const float bia0 = bout[cb + lr];
    const float bia1 = bout[cb + 16 + lr];

    #pragma unroll
    for (int rt = 0; rt < 4; rt++) {
        #pragma unroll
        for (int i = 0; i < 4; i++) {
            const int row = rt * 16 + lg * 4 + i;
            float v0 = acc[rt][0][i] + bia0;
            float v1 = acc[rt][1][i] + bia1;
            if (last) {
                out_logits[(size_t)row * Vn + cb + lr]      = v0;
                out_logits[(size_t)row * Vn + cb + 16 + lr] = v1;
            }
            float m = fmaxf(v0, v1);
            #pragma unroll
            for (int d = 1; d < 16; d <<= 1) m = fmaxf(m, __shfl_xor(m, d));
            float s = expf(v0 - m) + expf(v1 - m);
            #pragma unroll
            for (int d = 1; d < 16; d <<= 1) s += __shfl_xor(s, d);
            if (lr == 0) { sm[w][row] = m; ss[w][row] = s; }
        }
    }
    __syncthreads();
    if (t < Bn) {
        float M = sm[0][t], S = ss[0][t];
        #pragma unroll
        for (int ww = 1; ww < 4; ww++) {
            const float m2 = sm[ww][t], s2 = ss[ww][t];
            const float Mn = fmaxf(M, m2);
            S = S * expf(M - Mn) + s2 * expf(m2 - Mn);
            M = Mn;
        }
        pmax[blockIdx.x * Bn + t] = M;
        psum[blockIdx.x * Bn + t] = S;
    }
}

__global__ __launch_bounds__(256) void loss_kernel_fb(
    const float* __restrict__ pmax, const float* __restrict__ psum,
    const float* __restrict__ hn, const int* __restrict__ idx,
    const float* __restrict__ Wout, const float* __restrict__ bout,
    float* __restrict__ ws_loss, float* __restrict__ out_loss,
    int step, int last)
{
    __shared__ float ce[Bn];
    loss_body(pmax, psum, hn, idx, Wout, bout, ws_loss, out_loss, step, last, ce);
}

// ===========================================================================
extern "C" void kernel_launch(void* const* d_in, const int* in_sizes, int n_in,
                              void* d_out, int out_size, void* d_ws, size_t ws_size,
                              hipStream_t stream) {
    (void)in_sizes; (void)n_in; (void)out_size;
    const int*   idx    = (const int*)  d_in[0];
    const float* emb    = (const float*)d_in[3];
    const float* W_attn = (const float*)d_in[4];
    const float* b_attn = (const float*)d_in[5];
    const float* W_ih   = (const float*)d_in[6];
    const float* W_hh   = (const float*)d_in[7];
    const float* b_ih   = (const float*)d_in[8];
    const float* b_hh   = (const float*)d_in[9];
    const float* W_out  = (const float*)d_in[10];
    const float* b_out  = (const float*)d_in[11];

    float* out = (float*)d_out;
    float* out_attn   = out + 1;
    float* out_hfin   = out + 1 + (size_t)Tn * Bn * Lq;
    float* out_logits = out + 1 + (size_t)Tn * Bn * Lq + (size_t)Bn * Hn;

    if (ws_size >= FP_END) {
        // ------------------------- fast path -------------------------
        char* W = (char*)d_ws;
        float* loss  = (float*)(W + FP_LOSS);
        float* hf[2] = {(float*)(W + FP_HF0), (float*)(W + FP_HF1)};
        ushort_t* hhi[2] = {(ushort_t*)(W + FP_HHI0), (ushort_t*)(W + FP_HHI1)};
        ushort_t* hlo[2] = {(ushort_t*)(W + FP_HLO0), (ushort_t*)(W + FP_HLO1)};
        float* zh  = (float*)(W + FP_ZH);
        float* pm  = (float*)(W + FP_PM);
        float* ps  = (float*)(W + FP_PS);
        ushort_t* whhhi = (ushort_t*)(W + FP_WHHHI);
        ushort_t* whhlo = (ushort_t*)(W + FP_WHHLO);
        ushort_t* wahhi = (ushort_t*)(W + FP_WAHHI);
        ushort_t* wahlo = (ushort_t*)(W + FP_WAHLO);
        ushort_t* wo16  = (ushort_t*)(W + FP_WO16);
        float* Gi  = (float*)(W + FP_GI);
        float* Gax = (float*)(W + FP_GAX);

        zero_ws_kernel<<<dim3(545), dim3(256), 0, stream>>>(hf[0], zh, loss);
        split_w_kernel<<<dim3(3328), dim3(256), 0, stream>>>(W_hh, W_attn, whhhi, whhlo, wahhi, wahlo);
        wout_cvt_kernel<<<dim3(2048), dim3(256), 0, stream>>>(W_out, wo16);
        pre_gemm_kernel<<<dim3(Tn * 12), dim3(256), 0, stream>>>(idx, emb, W_ih, 512, b_ih, Gi, 1536, 12);
        pre_gemm_kernel<<<dim3(Tn), dim3(256), 0, stream>>>(idx, emb, W_attn, 1024, b_attn, Gax, 128, 1);

        // gates for step 0 (zh zeroed, h0 = 0)
        gates2_kernel<<<dim3(64), dim3(128), 0, stream>>>(
            zh, Gi, Gax, b_hh, hf[0], hf[1], hhi[1], hlo[1], out_attn, out_hfin, 0, 0);

        int cu = 1, pv = 0;
        for (int i = 0; i < Tn; i++) {
            const int last = (i == Tn - 1) ? 1 : 0;
            fused_step_kernel<<<dim3(264), dim3(256), 0, stream>>>(
                hhi[cu], hlo[cu], hf[pv], idx, wo16, W_out, b_out,
                whhhi, whhlo, wahhi, wahlo, zh, pm, ps, out_logits, loss, i, last);
            if (!last) {
                gates2_kernel<<<dim3(64), dim3(128), 0, stream>>>(
                    zh, Gi, Gax, b_hh, hf[cu], hf[pv], hhi[pv], hlo[pv],
                    out_attn, out_hfin, i + 1, (i + 1 == Tn - 1) ? 1 : 0);
                const int tmp = cu; cu = pv; pv = tmp;
            }
        }
        // step 126 parity = 0
        final_loss_kernel<<<dim3(1), dim3(256), 0, stream>>>(
            pm, ps, hf[cu], idx, W_out, b_out, loss, out);
    } else {
        // ---------------------- fallback (round-2) ----------------------
        float* ws  = (float*)d_ws;
        float* hA  = ws + OFF_HA;
        float* hB  = ws + OFF_HB;
        float* Z   = ws + OFF_Z;
        float* pmf = ws + OFF_PM;
        float* psf = ws + OFF_PS;
        ushort_t* hb16 = (ushort_t*)(ws + OFF_HBF);

        init_kernel<<<dim3(128), dim3(256), 0, stream>>>(ws);

        float* hc = hA;
        float* hx = hB;
        for (int i = 0; i < Tn; i++) {
            const int last = (i == Tn - 1) ? 1 : 0;
            z_kernel<<<dim3(26), dim3(256), 0, stream>>>(
                hc, idx, emb, W_attn, b_attn, W_ih, b_ih, W_hh, b_hh, Z, i,
                pmf, psf, W_out, b_out, ws + OFF_LOSS);
            gates_softmax_kernel<<<dim3(64), dim3(128), 0, stream>>>(
                Z, hc, hx, hb16, out_attn, out_hfin, i, last);
            logits_mfma_kernel<<<dim3(250), dim3(256), 0, stream>>>(
                hb16, W_out, b_out, pmf, psf, out_logits, last);
            float* tmp = hc; hc = hx; hx = tmp;
        }
        loss_kernel_fb<<<dim3(1), dim3(256), 0, stream>>>(
            pmf, psf, hc, idx, W_out, b_out, ws + OFF_LOSS, out, Tn - 1, 1);
    }
}

// Round 4
// 5706.426 us; speedup vs baseline: 4.2594x; 1.0347x over previous
//
#include <hip/hip_runtime.h>
#include <math.h>

// Problem constants
#define Bn 64      // batch
#define Lq 128     // output_length
#define En 512     // emb dim
#define Hn 512     // hidden
#define Vn 32000   // vocab
#define Tn 127     // steps = L-1
#define MR 8128    // Tn*Bn real rows of H_all
#define MP 8192    // padded rows
#define NCB 125    // big-gemm col blocks (256 cols each)
#define ZC3 3200   // zh row width: 128 attn | 1536 gh | 1536 gi

typedef __attribute__((ext_vector_type(8))) short short8v;  // 8 bf16
typedef __attribute__((ext_vector_type(4))) float f32x4;
typedef unsigned short ushort_t;

__device__ __forceinline__ ushort_t f2bf(float f) {
    unsigned u = __builtin_bit_cast(unsigned, f);
    u += 0x7fffu + ((u >> 16) & 1u);          // RNE
    return (ushort_t)(u >> 16);
}
__device__ __forceinline__ float bf2f(ushort_t h) {
    return __builtin_bit_cast(float, ((unsigned)h) << 16);
}

// ---------------- ws byte offsets ----------------
constexpr size_t FP_CET   = 0;                         // ce_t [127] f32 (+pad)
constexpr size_t FP_ZBH   = 512;                       // zero-h bf16 hi [64][512]
constexpr size_t FP_ZBL   = FP_ZBH  + 65536;
constexpr size_t FP_XH0   = FP_ZBL  + 65536;           // x bf16 hi/lo double-buffer
constexpr size_t FP_XL0   = FP_XH0  + 65536;
constexpr size_t FP_XH1   = FP_XL0  + 65536;
constexpr size_t FP_XL1   = FP_XH1  + 65536;
constexpr size_t FP_ZH    = FP_XL1  + 65536;           // zh fp32 [64][3200]
constexpr size_t FP_WAHH  = FP_ZH   + 819200;          // W_attn[:,512:] hi/lo bf16 [128][512]
constexpr size_t FP_WAHL  = FP_WAHH + 131072;
constexpr size_t FP_WHHH  = FP_WAHL + 131072;          // W_hh hi/lo bf16 [1536][512]
constexpr size_t FP_WHHL  = FP_WHHH + 1572864;
constexpr size_t FP_WIHH  = FP_WHHL + 1572864;         // W_ih hi/lo bf16 [1536][512]
constexpr size_t FP_WIHL  = FP_WIHH + 1572864;
constexpr size_t FP_WO16  = FP_WIHL + 1572864;         // W_out bf16 [32000][512]
constexpr size_t FP_GAX   = FP_WO16 + 32768000;        // Gax fp32 [127][64][128]
constexpr size_t FP_HHI   = FP_GAX  + 4161536;         // H_all bf16 hi [8192][512]
constexpr size_t FP_HLO   = FP_HHI  + 8388608;
constexpr size_t FP_PM    = FP_HLO  + 8388608;         // pmax [125][8192] f32
constexpr size_t FP_PS    = FP_PM   + 4096000;
constexpr size_t FP_END   = FP_PS   + 4096000;         // ~69.7 MB

// ---------------------------------------------------------------------------
// init: zero the h0 bf16 buffers + H_all pad rows; prep x_0 = split(emb[idx[:,0]])
// grid 256 x 256
// ---------------------------------------------------------------------------
__global__ __launch_bounds__(256) void init_misc_kernel(
    const int* __restrict__ idx, const float* __restrict__ emb,
    ushort_t* __restrict__ zbh, ushort_t* __restrict__ zbl,
    ushort_t* __restrict__ xh0, ushort_t* __restrict__ xl0,
    ushort_t* __restrict__ Hhi, ushort_t* __restrict__ Hlo)
{
    const int i = blockIdx.x * 256 + threadIdx.x;
    if (i < Bn * Hn) {
        zbh[i] = 0; zbl[i] = 0;
        const int b = i >> 9, u = i & 511;
        const float xv = emb[(size_t)idx[b * Lq] * En + u];
        const ushort_t hi = f2bf(xv);
        xh0[i] = hi;
        xl0[i] = f2bf(xv - bf2f(hi));
    } else {
        const int j = i - Bn * Hn;                  // pad rows 8128..8191
        Hhi[(size_t)MR * Hn + j] = 0;
        Hlo[(size_t)MR * Hn + j] = 0;
    }
}

// ---------------------------------------------------------------------------
// split W_hh, W_ih, W_attn[:,512:] into bf16 hi/lo. grid 6400 x 256
// ---------------------------------------------------------------------------
__global__ __launch_bounds__(256) void split_w_kernel(
    const float* __restrict__ Whh, const float* __restrict__ Wih,
    const float* __restrict__ Wattn,
    ushort_t* __restrict__ whhh, ushort_t* __restrict__ whhl,
    ushort_t* __restrict__ wihh, ushort_t* __restrict__ wihl,
    ushort_t* __restrict__ wahh, ushort_t* __restrict__ wahl)
{
    const int i = blockIdx.x * 256 + threadIdx.x;
    const int NW = 1536 * 512;
    if (i < NW) {
        const float w = Whh[i]; const ushort_t h = f2bf(w);
        whhh[i] = h; whhl[i] = f2bf(w - bf2f(h));
    } else if (i < 2 * NW) {
        const int e = i - NW;
        const float w = Wih[e]; const ushort_t h = f2bf(w);
        wihh[e] = h; wihl[e] = f2bf(w - bf2f(h));
    } else {
        const int e = i - 2 * NW;
        if (e < 128 * 512) {
            const int r = e >> 9, k = e & 511;
            const float w = Wattn[r * 1024 + 512 + k]; const ushort_t h = f2bf(w);
            wahh[e] = h; wahl[e] = f2bf(w - bf2f(h));
        }
    }
}

// W_out -> bf16 (grid-stride)
__global__ __launch_bounds__(256) void wout_cvt_kernel(
    const float* __restrict__ Wout, ushort_t* __restrict__ wo16)
{
    const size_t N = (size_t)Vn * Hn;
    for (size_t i = blockIdx.x * 256 + threadIdx.x; i < N; i += (size_t)gridDim.x * 256)
        wo16[i] = f2bf(Wout[i]);
}

// ---------------------------------------------------------------------------
// Gax[t] = emb[idx[:,t]] @ W_attn[:, :512].T + b_attn  (fp32, one-time, 127 blocks)
// ---------------------------------------------------------------------------
#define PA 68
#define PW 132
__global__ __launch_bounds__(256) void pre_gemm_kernel(
    const int* __restrict__ idx, const float* __restrict__ emb,
    const float* __restrict__ Wb, int ldw, const float* __restrict__ bias,
    float* __restrict__ outp, int ldo, int ncb)
{
    const int blk = blockIdx.x;
    const int ts  = blk / ncb;
    const int cbase = (blk % ncb) * 128;
    const int t  = threadIdx.x;
    const int tr = t >> 4, tc = t & 15;

    __shared__ float As[32 * PA];
    __shared__ float Ws[32 * PW];

    float acc[4][8];
    #pragma unroll
    for (int q = 0; q < 4; q++)
        #pragma unroll
        for (int j = 0; j < 8; j++) acc[q][j] = 0.0f;

    const int ab = t & 63, kq = t >> 6;
    const int wc = t >> 1, wh = t & 1;

    for (int k0 = 0; k0 < 512; k0 += 32) {
        {
            const float* ap = emb + (size_t)idx[ab * Lq + ts] * En + k0 + kq * 8;
            const float4 v0 = *reinterpret_cast<const float4*>(ap);
            const float4 v1 = *reinterpret_cast<const float4*>(ap + 4);
            const int kk = kq * 8;
            As[(kk + 0) * PA + ab] = v0.x;  As[(kk + 1) * PA + ab] = v0.y;
            As[(kk + 2) * PA + ab] = v0.z;  As[(kk + 3) * PA + ab] = v0.w;
            As[(kk + 4) * PA + ab] = v1.x;  As[(kk + 5) * PA + ab] = v1.y;
            As[(kk + 6) * PA + ab] = v1.z;  As[(kk + 7) * PA + ab] = v1.w;
        }
        {
            const float* wp = Wb + (size_t)(cbase + wc) * ldw + k0 + wh * 16;
            const float4 w0 = reinterpret_cast<const float4*>(wp)[0];
            const float4 w1 = reinterpret_cast<const float4*>(wp)[1];
            const float4 w2 = reinterpret_cast<const float4*>(wp)[2];
            const float4 w3 = reinterpret_cast<const float4*>(wp)[3];
            const int kk = wh * 16;
            Ws[(kk + 0 ) * PW + wc] = w0.x; Ws[(kk + 1 ) * PW + wc] = w0.y;
            Ws[(kk + 2 ) * PW + wc] = w0.z; Ws[(kk + 3 ) * PW + wc] = w0.w;
            Ws[(kk + 4 ) * PW + wc] = w1.x; Ws[(kk + 5 ) * PW + wc] = w1.y;
            Ws[(kk + 6 ) * PW + wc] = w1.z; Ws[(kk + 7 ) * PW + wc] = w1.w;
            Ws[(kk + 8 ) * PW + wc] = w2.x; Ws[(kk + 9 ) * PW + wc] = w2.y;
            Ws[(kk + 10) * PW + wc] = w2.z; Ws[(kk + 11) * PW + wc] = w2.w;
            Ws[(kk + 12) * PW + wc] = w3.x; Ws[(kk + 13) * PW + wc] = w3.y;
            Ws[(kk + 14) * PW + wc] = w3.z; Ws[(kk + 15) * PW + wc] = w3.w;
        }
        __syncthreads();
        #pragma unroll 4
        for (int kk = 0; kk < 32; kk++) {
            const float4 av = *reinterpret_cast<const float4*>(&As[kk * PA + tr * 4]);
            const float4 w0 = *reinterpret_cast<const float4*>(&Ws[kk * PW + tc * 8]);
            const float4 w1 = *reinterpret_cast<const float4*>(&Ws[kk * PW + tc * 8 + 4]);
            const float a0 = av.x, a1 = av.y, a2 = av.z, a3 = av.w;
            const float w[8] = {w0.x, w0.y, w0.z, w0.w, w1.x, w1.y, w1.z, w1.w};
            #pragma unroll
            for (int j = 0; j < 8; j++) {
                acc[0][j] = fmaf(a0, w[j], acc[0][j]);
                acc[1][j] = fmaf(a1, w[j], acc[1][j]);
                acc[2][j] = fmaf(a2, w[j], acc[2][j]);
                acc[3][j] = fmaf(a3, w[j], acc[3][j]);
            }
        }
        __syncthreads();
    }

    #pragma unroll
    for (int q = 0; q < 4; q++) {
        const int row = tr * 4 + q;
        #pragma unroll
        for (int j = 0; j < 8; j++) {
            const int lc = tc * 8 + j;
            outp[((size_t)ts * 64 + row) * ldo + cbase + lc] = acc[q][j] + bias[cbase + lc];
        }
    }
}

// ---------------------------------------------------------------------------
// zh_mfma_kernel: 25 blocks x 256 threads (4 waves). Per step s:
//   blk 0     : attn-h part  (A = h_s hi/lo,  W = wah)  -> zh[:,0:128)
//   blk 1..12 : gh           (A = h_s hi/lo,  W = whh)  -> zh[:,128:1664)
//   blk 13..24: gi           (A = x_s hi/lo,  W = wih)  -> zh[:,1664:3200)
// 3-term bf16 hi/lo split MFMA (hi*hi + lo*hi + hi*lo), no biases.
// ---------------------------------------------------------------------------
__global__ __launch_bounds__(256) void zh_mfma_kernel(
    const ushort_t* __restrict__ hhi, const ushort_t* __restrict__ hlo,
    const ushort_t* __restrict__ xhi, const ushort_t* __restrict__ xlo,
    const ushort_t* __restrict__ wahh, const ushort_t* __restrict__ wahl,
    const ushort_t* __restrict__ whhh, const ushort_t* __restrict__ whhl,
    const ushort_t* __restrict__ wihh, const ushort_t* __restrict__ wihl,
    float* __restrict__ zh)
{
    const int t = threadIdx.x;
    const int blk = blockIdx.x;
    const int w = t >> 6, l = t & 63;
    const int lr = l & 15, lg = l >> 4;

    const ushort_t *ahi, *alo, *whi, *wlo;
    int prow, zcb;
    if (blk == 0)      { ahi = hhi; alo = hlo; whi = wahh; wlo = wahl; prow = 0;              zcb = 0; }
    else if (blk <= 12){ ahi = hhi; alo = hlo; whi = whhh; wlo = whhl; prow = (blk-1)*128;    zcb = 128 + (blk-1)*128; }
    else               { ahi = xhi; alo = xlo; whi = wihh; wlo = wihl; prow = (blk-13)*128;   zcb = 1664 + (blk-13)*128; }

    const int wc = w * 32;

    f32x4 acc[4][2];
    #pragma unroll
    for (int rt = 0; rt < 4; rt++)
        #pragma unroll
        for (int ct = 0; ct < 2; ct++)
            acc[rt][ct] = (f32x4){0.f, 0.f, 0.f, 0.f};

    const ushort_t* ahip = ahi + lr * Hn + lg * 8;
    const ushort_t* alop = alo + lr * Hn + lg * 8;
    const ushort_t* bh0  = whi + (size_t)(prow + wc + lr) * Hn + lg * 8;
    const ushort_t* bh1  = bh0 + 16 * Hn;
    const ushort_t* bl0  = wlo + (size_t)(prow + wc + lr) * Hn + lg * 8;
    const ushort_t* bl1  = bl0 + 16 * Hn;

    #pragma unroll 2
    for (int ks = 0; ks < 16; ks++) {
        const int k0 = ks * 32;
        short8v av[4], lv[4];
        #pragma unroll
        for (int rt = 0; rt < 4; rt++) {
            av[rt] = *reinterpret_cast<const short8v*>(ahip + rt * (16 * Hn) + k0);
            lv[rt] = *reinterpret_cast<const short8v*>(alop + rt * (16 * Hn) + k0);
        }
        const short8v vh0 = *reinterpret_cast<const short8v*>(bh0 + k0);
        const short8v vh1 = *reinterpret_cast<const short8v*>(bh1 + k0);
        const short8v vl0 = *reinterpret_cast<const short8v*>(bl0 + k0);
        const short8v vl1 = *reinterpret_cast<const short8v*>(bl1 + k0);
        #pragma unroll
        for (int rt = 0; rt < 4; rt++) {
            acc[rt][0] = __builtin_amdgcn_mfma_f32_16x16x32_bf16(av[rt], vh0, acc[rt][0], 0, 0, 0);
            acc[rt][0] = __builtin_amdgcn_mfma_f32_16x16x32_bf16(lv[rt], vh0, acc[rt][0], 0, 0, 0);
            acc[rt][0] = __builtin_amdgcn_mfma_f32_16x16x32_bf16(av[rt], vl0, acc[rt][0], 0, 0, 0);
            acc[rt][1] = __builtin_amdgcn_mfma_f32_16x16x32_bf16(av[rt], vh1, acc[rt][1], 0, 0, 0);
            acc[rt][1] = __builtin_amdgcn_mfma_f32_16x16x32_bf16(lv[rt], vh1, acc[rt][1], 0, 0, 0);
            acc[rt][1] = __builtin_amdgcn_mfma_f32_16x16x32_bf16(av[rt], vl1, acc[rt][1], 0, 0, 0);
        }
    }

    #pragma unroll
    for (int rt = 0; rt < 4; rt++) {
        #pragma unroll
        for (int i = 0; i < 4; i++) {
            const int row = rt * 16 + lg * 4 + i;
            zh[row * ZC3 + zcb + wc + lr]      = acc[rt][0][i];
            zh[row * ZC3 + zcb + wc + 16 + lr] = acc[rt][1][i];
        }
    }
}

// ---------------------------------------------------------------------------
// gates_kernel: 64 blocks x 128 threads. Softmax(attn) -> out_attn[s];
// GRU gates (+biases) -> h_{s+1} stored into H_all[s] (bf16 hi/lo);
// prep x_{s+1} split for the next zh.
// ---------------------------------------------------------------------------
__global__ __launch_bounds__(128) void gates_kernel(
    const float* __restrict__ zh, const float* __restrict__ Gax,
    const float* __restrict__ b_ih, const float* __restrict__ b_hh,
    const ushort_t* __restrict__ hhi, const ushort_t* __restrict__ hlo,
    const int* __restrict__ idx, const float* __restrict__ emb,
    ushort_t* __restrict__ Hhi, ushort_t* __restrict__ Hlo,
    ushort_t* __restrict__ xhn, ushort_t* __restrict__ xln,
    float* __restrict__ out_attn, float* __restrict__ out_hfin, int s)
{
    const int b = blockIdx.x;
    const int t = threadIdx.x;
    __shared__ float red[128];

    const int jp = (s > 0) ? (s - 1) : 0;
    const float x = zh[b * ZC3 + t] + Gax[(size_t)jp * (Bn * Lq) + b * Lq + t];
    red[t] = x; __syncthreads();
    for (int st = 64; st > 0; st >>= 1) {
        if (t < st) red[t] = fmaxf(red[t], red[t + st]);
        __syncthreads();
    }
    const float M = red[0];
    __syncthreads();
    const float e = expf(x - M);
    red[t] = e; __syncthreads();
    for (int st = 64; st > 0; st >>= 1) {
        if (t < st) red[t] += red[t + st];
        __syncthreads();
    }
    const float S = red[0];
    out_attn[((size_t)s * Bn + b) * Lq + t] = e / S;

    #pragma unroll
    for (int q = 0; q < 4; q++) {
        const int u = t + q * 128;
        const float gir = zh[b * ZC3 + 1664 + u] + b_ih[u];
        const float giz = zh[b * ZC3 + 2176 + u] + b_ih[512 + u];
        const float gin = zh[b * ZC3 + 2688 + u] + b_ih[1024 + u];
        const float ghr = zh[b * ZC3 + 128  + u] + b_hh[u];
        const float ghz = zh[b * ZC3 + 640  + u] + b_hh[512 + u];
        const float ghn = zh[b * ZC3 + 1152 + u] + b_hh[1024 + u];
        const float r  = 1.0f / (1.0f + expf(-(gir + ghr)));
        const float zg = 1.0f / (1.0f + expf(-(giz + ghz)));
        const float n  = tanhf(gin + r * ghn);
        const float hv = bf2f(hhi[b * Hn + u]) + bf2f(hlo[b * Hn + u]);
        const float hnew = (1.0f - zg) * n + zg * hv;
        const ushort_t hi = f2bf(hnew);
        Hhi[((size_t)s * Bn + b) * Hn + u] = hi;
        Hlo[((size_t)s * Bn + b) * Hn + u] = f2bf(hnew - bf2f(hi));
        if (s < Tn - 1) {
            const float xv = emb[(size_t)idx[b * Lq + s + 1] * En + u];
            const ushort_t xh = f2bf(xv);
            xhn[b * Hn + u] = xh;
            xln[b * Hn + u] = f2bf(xv - bf2f(xh));
        }
        if (s == Tn - 1) out_hfin[b * Hn + u] = hnew;
    }
}

// ---------------------------------------------------------------------------
// big_gemm_kernel: H_all[8192x512]bf16 @ wo16.T -> per-block (rowmax,sumexp)
// partials + last-step logits. Tile 128x256, 512 threads (8 waves 2x4).
// grid = 125 cb x 64 rb, rb-fast so consecutive blocks share the B panel (L2).
// ---------------------------------------------------------------------------
__global__ __launch_bounds__(512) void big_gemm_kernel(
    const ushort_t* __restrict__ Hhi, const ushort_t* __restrict__ wo16,
    const float* __restrict__ bout,
    float* __restrict__ pm, float* __restrict__ ps,
    float* __restrict__ out_logits)
{
    const int bid = blockIdx.x;
    const int cb = bid >> 6;       // 0..124
    const int rb = bid & 63;       // 0..63
    const int t = threadIdx.x;
    const int w = t >> 6, l = t & 63;
    const int wr = w >> 2, wc = w & 3;
    const int lr = l & 15, lg = l >> 4;

    const int Ab = rb * 128 + wr * 64;
    const int Bb = cb * 256 + wc * 64;

    f32x4 acc[4][4];
    #pragma unroll
    for (int rt = 0; rt < 4; rt++)
        #pragma unroll
        for (int ct = 0; ct < 4; ct++)
            acc[rt][ct] = (f32x4){0.f, 0.f, 0.f, 0.f};

    const ushort_t* ap = Hhi  + (size_t)(Ab + lr) * Hn + lg * 8;
    const ushort_t* bp = wo16 + (size_t)(Bb + lr) * Hn + lg * 8;

    #pragma unroll 2
    for (int ks = 0; ks < 16; ks++) {
        const int k0 = ks * 32;
        short8v a[4], bv[4];
        #pragma unroll
        for (int rt = 0; rt < 4; rt++)
            a[rt] = *reinterpret_cast<const short8v*>(ap + rt * (16 * Hn) + k0);
        #pragma unroll
        for (int ct = 0; ct < 4; ct++)
            bv[ct] = *reinterpret_cast<const short8v*>(bp + ct * (16 * Hn) + k0);
        #pragma unroll
        for (int rt = 0; rt < 4; rt++)
            #pragma unroll
            for (int ct = 0; ct < 4; ct++)
                acc[rt][ct] = __builtin_amdgcn_mfma_f32_16x16x32_bf16(a[rt], bv[ct], acc[rt][ct], 0, 0, 0);
    }

    const float bia0 = bout[Bb + lr];
    const float bia1 = bout[Bb + 16 + lr];
    const float bia2 = bout[Bb + 32 + lr];
    const float bia3 = bout[Bb + 48 + lr];

    __shared__ float sm[8][64];
    __shared__ float ss[8][64];

    #pragma unroll
    for (int rt = 0; rt < 4; rt++) {
        #pragma unroll
        for (int i = 0; i < 4; i++) {
            const int row_l = rt * 16 + lg * 4 + i;       // within this wave's 64 rows
            const int grow = rb * 128 + wr * 64 + row_l;  // global H_all row
            float v0 = acc[rt][0][i] + bia0;
            float v1 = acc[rt][1][i] + bia1;
            float v2 = acc[rt][2][i] + bia2;
            float v3 = acc[rt][3][i] + bia3;
            if (grow >= MR - Bn && grow < MR) {           // last step: emit logits
                const size_t ob = (size_t)(grow - (MR - Bn)) * Vn + Bb + lr;
                out_logits[ob]      = v0;
                out_logits[ob + 16] = v1;
                out_logits[ob + 32] = v2;
                out_logits[ob + 48] = v3;
            }
            float m = fmaxf(fmaxf(v0, v1), fmaxf(v2, v3));
            #pragma unroll
            for (int d = 1; d < 16; d <<= 1) m = fmaxf(m, __shfl_xor(m, d));
            float sv = expf(v0 - m) + expf(v1 - m) + expf(v2 - m) + expf(v3 - m);
            #pragma unroll
            for (int d = 1; d < 16; d <<= 1) sv += __shfl_xor(sv, d);
            if (lr == 0) { sm[w][row_l] = m; ss[w][row_l] = sv; }
        }
    }
    __syncthreads();
    if (t < 128) {
        const int wrg = t >> 6, lrow = t & 63;
        float M = sm[wrg * 4 + 0][lrow], S = ss[wrg * 4 + 0][lrow];
        #pragma unroll
        for (int qc = 1; qc < 4; qc++) {
            const float m2 = sm[wrg * 4 + qc][lrow], s2 = ss[wrg * 4 + qc][lrow];
            const float Mn = fmaxf(M, m2);
            S = S * expf(M - Mn) + s2 * expf(m2 - Mn);
            M = Mn;
        }
        pm[(size_t)cb * MP + rb * 128 + t] = M;
        ps[(size_t)cb * MP + rb * 128 + t] = S;
    }
}

// ---------------------------------------------------------------------------
// merge_loss_kernel: 127 blocks x 256 threads. Block t: merge 125 partials per
// row, target-logit dot (hi+lo ~ fp32), per-step mean CE -> ce_t[t].
// ---------------------------------------------------------------------------
__global__ __launch_bounds__(256) void merge_loss_kernel(
    const float* __restrict__ pm, const float* __restrict__ ps,
    const ushort_t* __restrict__ Hhi, const ushort_t* __restrict__ Hlo,
    const int* __restrict__ idx, const float* __restrict__ Wout,
    const float* __restrict__ bout, float* __restrict__ ce_t)
{
    const int tt = blockIdx.x;
    const int t = threadIdx.x;
    const int b = t >> 2, q = t & 3;
    const int grow = tt * 64 + b;

    float M = -INFINITY, S = 0.0f;
    for (int p = q; p < NCB; p += 4) {
        const float m2 = pm[(size_t)p * MP + grow], s2 = ps[(size_t)p * MP + grow];
        const float Mn = fmaxf(M, m2);
        S = S * expf(M - Mn) + s2 * expf(m2 - Mn);
        M = Mn;
    }
    #pragma unroll
    for (int d = 1; d < 4; d <<= 1) {
        const float m2 = __shfl_xor(M, d, 4);
        const float s2 = __shfl_xor(S, d, 4);
        const float Mn = fmaxf(M, m2);
        S = S * expf(M - Mn) + s2 * expf(m2 - Mn);
        M = Mn;
    }

    const int tgt = idx[b * Lq + tt];
    const size_t hb = (size_t)grow * Hn;
    const float* wr_ = Wout + (size_t)tgt * Hn;
    float dot = 0.0f;
    for (int k = q * 128; k < q * 128 + 128; k += 4) {
        #pragma unroll
        for (int j = 0; j < 4; j++) {
            const float hv = bf2f(Hhi[hb + k + j]) + bf2f(Hlo[hb + k + j]);
            dot = fmaf(hv, wr_[k + j], dot);
        }
    }
    #pragma unroll
    for (int d = 1; d < 4; d <<= 1) dot += __shfl_xor(dot, d, 4);

    __shared__ float ce[Bn];
    if (q == 0) ce[b] = -(dot + bout[tgt] - M - logf(S));
    __syncthreads();
    if (t == 0) {
        float s = 0.0f;
        for (int i = 0; i < Bn; i++) s += ce[i];
        ce_t[tt] = s * (1.0f / Bn);
    }
}

__global__ __launch_bounds__(128) void final_sum_kernel(
    const float* __restrict__ ce_t, float* __restrict__ out)
{
    __shared__ float red[128];
    const int t = threadIdx.x;
    red[t] = (t < Tn) ? ce_t[t] : 0.0f;
    __syncthreads();
    for (int st = 64; st > 0; st >>= 1) {
        if (t < st) red[t] += red[t + st];
        __syncthreads();
    }
    if (t == 0) out[0] = red[0];
}

// ===========================================================================
extern "C" void kernel_launch(void* const* d_in, const int* in_sizes, int n_in,
                              void* d_out, int out_size, void* d_ws, size_t ws_size,
                              hipStream_t stream) {
    (void)in_sizes; (void)n_in; (void)out_size; (void)ws_size;
    const int*   idx    = (const int*)  d_in[0];
    const float* emb    = (const float*)d_in[3];
    const float* W_attn = (const float*)d_in[4];
    const float* b_attn = (const float*)d_in[5];
    const float* W_ih   = (const float*)d_in[6];
    const float* W_hh   = (const float*)d_in[7];
    const float* b_ih   = (const float*)d_in[8];
    const float* b_hh   = (const float*)d_in[9];
    const float* W_out  = (const float*)d_in[10];
    const float* b_out  = (const float*)d_in[11];

    float* out = (float*)d_out;
    float* out_attn   = out + 1;
    float* out_hfin   = out + 1 + (size_t)Tn * Bn * Lq;
    float* out_logits = out + 1 + (size_t)Tn * Bn * Lq + (size_t)Bn * Hn;

    char* W = (char*)d_ws;
    float*    ce_t = (float*)   (W + FP_CET);
    ushort_t* zbh  = (ushort_t*)(W + FP_ZBH);
    ushort_t* zbl  = (ushort_t*)(W + FP_ZBL);
    ushort_t* xh[2] = {(ushort_t*)(W + FP_XH0), (ushort_t*)(W + FP_XH1)};
    ushort_t* xl[2] = {(ushort_t*)(W + FP_XL0), (ushort_t*)(W + FP_XL1)};
    float*    zh   = (float*)   (W + FP_ZH);
    ushort_t* wahh = (ushort_t*)(W + FP_WAHH);
    ushort_t* wahl = (ushort_t*)(W + FP_WAHL);
    ushort_t* whhh = (ushort_t*)(W + FP_WHHH);
    ushort_t* whhl = (ushort_t*)(W + FP_WHHL);
    ushort_t* wihh = (ushort_t*)(W + FP_WIHH);
    ushort_t* wihl = (ushort_t*)(W + FP_WIHL);
    ushort_t* wo16 = (ushort_t*)(W + FP_WO16);
    float*    Gax  = (float*)   (W + FP_GAX);
    ushort_t* Hhi  = (ushort_t*)(W + FP_HHI);
    ushort_t* Hlo  = (ushort_t*)(W + FP_HLO);
    float*    pm   = (float*)   (W + FP_PM);
    float*    ps   = (float*)   (W + FP_PS);

    // -------- phase 0: parallel precompute --------
    init_misc_kernel<<<dim3(256), dim3(256), 0, stream>>>(idx, emb, zbh, zbl, xh[0], xl[0], Hhi, Hlo);
    split_w_kernel<<<dim3(6400), dim3(256), 0, stream>>>(W_hh, W_ih, W_attn, whhh, whhl, wihh, wihl, wahh, wahl);
    wout_cvt_kernel<<<dim3(2048), dim3(256), 0, stream>>>(W_out, wo16);
    pre_gemm_kernel<<<dim3(Tn), dim3(256), 0, stream>>>(idx, emb, W_attn, 1024, b_attn, Gax, 128, 1);

    // -------- phase 1: sequential recurrence (tiny kernels only) --------
    for (int s = 0; s < Tn; s++) {
        const ushort_t* hhi_s = (s == 0) ? zbh : Hhi + (size_t)(s - 1) * Bn * Hn;
        const ushort_t* hlo_s = (s == 0) ? zbl : Hlo + (size_t)(s - 1) * Bn * Hn;
        zh_mfma_kernel<<<dim3(25), dim3(256), 0, stream>>>(
            hhi_s, hlo_s, xh[s & 1], xl[s & 1],
            wahh, wahl, whhh, whhl, wihh, wihl, zh);
        gates_kernel<<<dim3(64), dim3(128), 0, stream>>>(
            zh, Gax, b_ih, b_hh, hhi_s, hlo_s, idx, emb,
            Hhi, Hlo, xh[(s + 1) & 1], xl[(s + 1) & 1],
            out_attn, out_hfin, s);
    }

    // -------- phase 2: one big parallel GEMM + LSE partials --------
    big_gemm_kernel<<<dim3(NCB * 64), dim3(512), 0, stream>>>(
        Hhi, wo16, b_out, pm, ps, out_logits);

    // -------- phase 3: merge partials + CE --------
    merge_loss_kernel<<<dim3(Tn), dim3(256), 0, stream>>>(
        pm, ps, Hhi, Hlo, idx, W_out, b_out, ce_t);
    final_sum_kernel<<<dim3(1), dim3(128), 0, stream>>>(ce_t, out);
}

// Round 5
// 3510.180 us; speedup vs baseline: 6.9244x; 1.6257x over previous
//
#include <hip/hip_runtime.h>
#include <math.h>

// Problem constants
#define Bn 64      // batch
#define Lq 128     // output_length
#define En 512     // emb dim
#define Hn 512     // hidden
#define Vn 32000   // vocab
#define Tn 127     // steps = L-1
#define MR 8128    // Tn*Bn real rows of H_all
#define MP 8192    // padded rows
#define NCB2 250   // big-gemm col blocks (128 cols each)
#define NBLK 36u   // persistent recurrence blocks

typedef __attribute__((ext_vector_type(8))) short short8v;  // 8 bf16
typedef __attribute__((ext_vector_type(4))) float f32x4;
typedef unsigned short ushort_t;

__device__ __forceinline__ ushort_t f2bf(float f) {
    unsigned u = __builtin_bit_cast(unsigned, f);
    u += 0x7fffu + ((u >> 16) & 1u);          // RNE
    return (ushort_t)(u >> 16);
}
__device__ __forceinline__ float bf2f(ushort_t h) {
    return __builtin_bit_cast(float, ((unsigned)h) << 16);
}

// ---------------- ws byte offsets ----------------
// fixed region
constexpr size_t WS_BAR  = 0;                          // 64 B barrier counter
constexpr size_t WS_ZBH  = 64;                         // zero-h bf16 [64][512]
constexpr size_t WS_ZBL  = WS_ZBH + 65536;
constexpr size_t WS_WHHH = WS_ZBL + 65536;             // W_hh hi/lo bf16 [1536][512]
constexpr size_t WS_WHHL = WS_WHHH + 1572864;
constexpr size_t WS_WAHH = WS_WHHL + 1572864;          // W_attn[:,512:] hi/lo [128][512]
constexpr size_t WS_WAHL = WS_WAHH + 131072;
constexpr size_t WS_HHI  = WS_WAHL + 131072;           // H_all bf16 hi [8192][512]
constexpr size_t WS_HLO  = WS_HHI + 8388608;
constexpr size_t WS_U    = WS_HLO + 8388608;           // union region (20,316,224)
// phase-1 view of U: Gi fp32 [127][64][1536] (49,938,432) | Gax fp32 [127][64][128] (4,161,536)
constexpr size_t WS_GI   = WS_U;
constexpr size_t WS_GAX  = WS_U + 49938432;
// phase-2 view of U: wo16 bf16 [32000][512] (32,768,000) | pm (8,192,000) | ps
constexpr size_t WS_WO16 = WS_U;
constexpr size_t WS_PM   = WS_U + 32768000;
constexpr size_t WS_PS   = WS_PM + 8192000;

// ---------------------------------------------------------------------------
// grid barrier: monotonic counter, agent scope. All NBLK blocks co-resident
// (36 blocks << 256 CUs, launched into an idle device).
// ---------------------------------------------------------------------------
__device__ __forceinline__ void grid_bar(unsigned* bar, unsigned tgt) {
    __syncthreads();
    if (threadIdx.x == 0) {
        __hip_atomic_fetch_add(bar, 1u, __ATOMIC_ACQ_REL, __HIP_MEMORY_SCOPE_AGENT);
        while (__hip_atomic_load(bar, __ATOMIC_RELAXED, __HIP_MEMORY_SCOPE_AGENT) < tgt) { }
        (void)__hip_atomic_load(bar, __ATOMIC_ACQUIRE, __HIP_MEMORY_SCOPE_AGENT);
    }
    __syncthreads();
}

// ---------------------------------------------------------------------------
// setup_kernel: grid 3584 x 256.
//  blocks 0..255   : zero zbh/zbl, H pad rows, barrier, out[0]
//  blocks 256..3583: split W_hh and W_attn[:,512:] into bf16 hi/lo
// ---------------------------------------------------------------------------
__global__ __launch_bounds__(256) void setup_kernel(
    const float* __restrict__ Whh, const float* __restrict__ Wattn,
    ushort_t* __restrict__ zbh, ushort_t* __restrict__ zbl,
    ushort_t* __restrict__ whhh, ushort_t* __restrict__ whhl,
    ushort_t* __restrict__ wahh, ushort_t* __restrict__ wahl,
    ushort_t* __restrict__ Hhi, ushort_t* __restrict__ Hlo,
    unsigned* __restrict__ bar, float* __restrict__ out0)
{
    const int blk = blockIdx.x;
    const int t = threadIdx.x;
    if (blk < 256) {
        const int i = blk * 256 + t;
        if (i < Bn * Hn) { zbh[i] = 0; zbl[i] = 0; }
        else if (i < 2 * Bn * Hn) {
            const int j = i - Bn * Hn;
            Hhi[(size_t)MR * Hn + j] = 0;
            Hlo[(size_t)MR * Hn + j] = 0;
        }
        if (i == 0) { bar[0] = 0u; out0[0] = 0.0f; }
    } else {
        const int e = (blk - 256) * 256 + t;
        const int NW = 1536 * 512;
        if (e < NW) {
            const float wv = Whh[e]; const ushort_t h = f2bf(wv);
            whhh[e] = h; whhl[e] = f2bf(wv - bf2f(h));
        } else {
            const int e2 = e - NW;
            if (e2 < 128 * 512) {
                const int r = e2 >> 9, k = e2 & 511;
                const float wv = Wattn[r * 1024 + 512 + k]; const ushort_t h = f2bf(wv);
                wahh[e2] = h; wahl[e2] = f2bf(wv - bf2f(h));
            }
        }
    }
}

// W_out -> bf16 (grid-stride); runs AFTER recurrence (wo16 aliases Gi region)
__global__ __launch_bounds__(256) void wout_cvt_kernel(
    const float* __restrict__ Wout, ushort_t* __restrict__ wo16)
{
    const size_t N = (size_t)Vn * Hn;
    for (size_t i = blockIdx.x * 256 + threadIdx.x; i < N; i += (size_t)gridDim.x * 256)
        wo16[i] = f2bf(Wout[i]);
}

// ---------------------------------------------------------------------------
// fp32 tile GEMM body (proven): out[ts][64][ldo] tile at cbase,
// A = emb[idx[:,ts]], B = Wb rows (first 512 cols), + bias.
// ---------------------------------------------------------------------------
#define PA 68
#define PW 132
__device__ void pre_tile(
    const int* __restrict__ idx, const float* __restrict__ emb,
    const float* __restrict__ Wb, int ldw, const float* __restrict__ bias,
    float* __restrict__ outp, int ldo, int ts, int cbase,
    float* As, float* Ws)
{
    const int t  = threadIdx.x;
    const int tr = t >> 4, tc = t & 15;

    float acc[4][8];
    #pragma unroll
    for (int q = 0; q < 4; q++)
        #pragma unroll
        for (int j = 0; j < 8; j++) acc[q][j] = 0.0f;

    const int ab = t & 63, kq = t >> 6;
    const int wc = t >> 1, wh = t & 1;

    for (int k0 = 0; k0 < 512; k0 += 32) {
        {
            const float* ap = emb + (size_t)idx[ab * Lq + ts] * En + k0 + kq * 8;
            const float4 v0 = *reinterpret_cast<const float4*>(ap);
            const float4 v1 = *reinterpret_cast<const float4*>(ap + 4);
            const int kk = kq * 8;
            As[(kk + 0) * PA + ab] = v0.x;  As[(kk + 1) * PA + ab] = v0.y;
            As[(kk + 2) * PA + ab] = v0.z;  As[(kk + 3) * PA + ab] = v0.w;
            As[(kk + 4) * PA + ab] = v1.x;  As[(kk + 5) * PA + ab] = v1.y;
            As[(kk + 6) * PA + ab] = v1.z;  As[(kk + 7) * PA + ab] = v1.w;
        }
        {
            const float* wp = Wb + (size_t)(cbase + wc) * ldw + k0 + wh * 16;
            const float4 w0 = reinterpret_cast<const float4*>(wp)[0];
            const float4 w1 = reinterpret_cast<const float4*>(wp)[1];
            const float4 w2 = reinterpret_cast<const float4*>(wp)[2];
            const float4 w3 = reinterpret_cast<const float4*>(wp)[3];
            const int kk = wh * 16;
            Ws[(kk + 0 ) * PW + wc] = w0.x; Ws[(kk + 1 ) * PW + wc] = w0.y;
            Ws[(kk + 2 ) * PW + wc] = w0.z; Ws[(kk + 3 ) * PW + wc] = w0.w;
            Ws[(kk + 4 ) * PW + wc] = w1.x; Ws[(kk + 5 ) * PW + wc] = w1.y;
            Ws[(kk + 6 ) * PW + wc] = w1.z; Ws[(kk + 7 ) * PW + wc] = w1.w;
            Ws[(kk + 8 ) * PW + wc] = w2.x; Ws[(kk + 9 ) * PW + wc] = w2.y;
            Ws[(kk + 10) * PW + wc] = w2.z; Ws[(kk + 11) * PW + wc] = w2.w;
            Ws[(kk + 12) * PW + wc] = w3.x; Ws[(kk + 13) * PW + wc] = w3.y;
            Ws[(kk + 14) * PW + wc] = w3.z; Ws[(kk + 15) * PW + wc] = w3.w;
        }
        __syncthreads();
        #pragma unroll 4
        for (int kk = 0; kk < 32; kk++) {
            const float4 av = *reinterpret_cast<const float4*>(&As[kk * PA + tr * 4]);
            const float4 w0 = *reinterpret_cast<const float4*>(&Ws[kk * PW + tc * 8]);
            const float4 w1 = *reinterpret_cast<const float4*>(&Ws[kk * PW + tc * 8 + 4]);
            const float a0 = av.x, a1 = av.y, a2 = av.z, a3 = av.w;
            const float w[8] = {w0.x, w0.y, w0.z, w0.w, w1.x, w1.y, w1.z, w1.w};
            #pragma unroll
            for (int j = 0; j < 8; j++) {
                acc[0][j] = fmaf(a0, w[j], acc[0][j]);
                acc[1][j] = fmaf(a1, w[j], acc[1][j]);
                acc[2][j] = fmaf(a2, w[j], acc[2][j]);
                acc[3][j] = fmaf(a3, w[j], acc[3][j]);
            }
        }
        __syncthreads();
    }

    #pragma unroll
    for (int q = 0; q < 4; q++) {
        const int row = tr * 4 + q;
        #pragma unroll
        for (int j = 0; j < 8; j++) {
            const int lc = tc * 8 + j;
            outp[((size_t)ts * 64 + row) * ldo + cbase + lc] = acc[q][j] + bias[cbase + lc];
        }
    }
}

// pre_all: blocks 0..1523 -> Gi (12 col-blocks x 127 steps); 1524..1650 -> Gax
__global__ __launch_bounds__(256) void pre_all_kernel(
    const int* __restrict__ idx, const float* __restrict__ emb,
    const float* __restrict__ Wih, const float* __restrict__ bih,
    const float* __restrict__ Wattn, const float* __restrict__ battn,
    float* __restrict__ Gi, float* __restrict__ Gax)
{
    __shared__ float As[32 * PA];
    __shared__ float Ws[32 * PW];
    const int blk = blockIdx.x;
    if (blk < Tn * 12) {
        pre_tile(idx, emb, Wih, 512, bih, Gi, 1536, blk / 12, (blk % 12) * 128, As, Ws);
    } else {
        pre_tile(idx, emb, Wattn, 1024, battn, Gax, 128, blk - Tn * 12, 0, As, Ws);
    }
}

// ---------------------------------------------------------------------------
// recur_kernel: PERSISTENT, grid 36 x 256, one launch for all 127 steps.
//  blocks 0..31 : GRU. block (rq,us)=(blk>>3, blk&7): rows rq*16..+16,
//                 u-cols us*64..+64. Wave w owns cols u0+w*16..+16 for the
//                 matched (r,z,n) gate triplet -> gates applied in-register.
//  blocks 32..35: attn. block aq: rows aq*16..+16, all 128 attn cols +
//                 Gax[max(s-1,0)] + row softmax -> out_attn[s].
// One grid barrier per step. gh / attn-h use 3-term bf16 hi/lo split MFMA.
// ---------------------------------------------------------------------------
__global__ __launch_bounds__(256) void recur_kernel(
    const ushort_t* __restrict__ zbh, const ushort_t* __restrict__ zbl,
    const ushort_t* __restrict__ whhh, const ushort_t* __restrict__ whhl,
    const ushort_t* __restrict__ wahh, const ushort_t* __restrict__ wahl,
    const float* __restrict__ Gi, const float* __restrict__ Gax,
    const float* __restrict__ b_hh,
    ushort_t* __restrict__ Hhi, ushort_t* __restrict__ Hlo,
    float* __restrict__ out_attn, float* __restrict__ out_hfin,
    unsigned* __restrict__ bar)
{
    __shared__ float lS[16][128];
    const int blk = blockIdx.x;
    const int t = threadIdx.x;
    const int w = t >> 6, l = t & 63, lr = l & 15, lg = l >> 4;

    if (blk < 32) {
        const int r0 = (blk >> 3) * 16;
        const int u0 = (blk & 7) * 64;
        const int c  = u0 + w * 16 + lr;
        const ushort_t* bh0 = whhh + (size_t)(c)        * Hn + lg * 8;
        const ushort_t* bh1 = whhh + (size_t)(512 + c)  * Hn + lg * 8;
        const ushort_t* bh2 = whhh + (size_t)(1024 + c) * Hn + lg * 8;
        const ushort_t* bl0 = whhl + (size_t)(c)        * Hn + lg * 8;
        const ushort_t* bl1 = whhl + (size_t)(512 + c)  * Hn + lg * 8;
        const ushort_t* bl2 = whhl + (size_t)(1024 + c) * Hn + lg * 8;
        const float bhr = b_hh[c], bhz = b_hh[512 + c], bhn = b_hh[1024 + c];

        for (int s = 0; s < Tn; s++) {
            const ushort_t* hh = (s == 0) ? zbh : (Hhi + (size_t)(s - 1) * (Bn * Hn));
            const ushort_t* hl = (s == 0) ? zbl : (Hlo + (size_t)(s - 1) * (Bn * Hn));
            const ushort_t* ah = hh + (size_t)(r0 + lr) * Hn + lg * 8;
            const ushort_t* al = hl + (size_t)(r0 + lr) * Hn + lg * 8;

            f32x4 a0 = {0.f,0.f,0.f,0.f}, a1 = {0.f,0.f,0.f,0.f}, a2 = {0.f,0.f,0.f,0.f};
            #pragma unroll 2
            for (int ks = 0; ks < 16; ks++) {
                const int k0 = ks * 32;
                const short8v xh  = *reinterpret_cast<const short8v*>(ah + k0);
                const short8v xlo = *reinterpret_cast<const short8v*>(al + k0);
                const short8v w0h = *reinterpret_cast<const short8v*>(bh0 + k0);
                const short8v w1h = *reinterpret_cast<const short8v*>(bh1 + k0);
                const short8v w2h = *reinterpret_cast<const short8v*>(bh2 + k0);
                const short8v w0l = *reinterpret_cast<const short8v*>(bl0 + k0);
                const short8v w1l = *reinterpret_cast<const short8v*>(bl1 + k0);
                const short8v w2l = *reinterpret_cast<const short8v*>(bl2 + k0);
                a0 = __builtin_amdgcn_mfma_f32_16x16x32_bf16(xh,  w0h, a0, 0, 0, 0);
                a0 = __builtin_amdgcn_mfma_f32_16x16x32_bf16(xlo, w0h, a0, 0, 0, 0);
                a0 = __builtin_amdgcn_mfma_f32_16x16x32_bf16(xh,  w0l, a0, 0, 0, 0);
                a1 = __builtin_amdgcn_mfma_f32_16x16x32_bf16(xh,  w1h, a1, 0, 0, 0);
                a1 = __builtin_amdgcn_mfma_f32_16x16x32_bf16(xlo, w1h, a1, 0, 0, 0);
                a1 = __builtin_amdgcn_mfma_f32_16x16x32_bf16(xh,  w1l, a1, 0, 0, 0);
                a2 = __builtin_amdgcn_mfma_f32_16x16x32_bf16(xh,  w2h, a2, 0, 0, 0);
                a2 = __builtin_amdgcn_mfma_f32_16x16x32_bf16(xlo, w2h, a2, 0, 0, 0);
                a2 = __builtin_amdgcn_mfma_f32_16x16x32_bf16(xh,  w2l, a2, 0, 0, 0);
            }
            #pragma unroll
            for (int i = 0; i < 4; i++) {
                const int grow = r0 + lg * 4 + i;
                const float* gib = Gi + ((size_t)s * Bn + grow) * 1536 + c;
                const float gir = gib[0], giz = gib[512], gin = gib[1024];
                const float ghr = a0[i] + bhr, ghz = a1[i] + bhz, ghn = a2[i] + bhn;
                const float rr = 1.0f / (1.0f + expf(-(gir + ghr)));
                const float zz = 1.0f / (1.0f + expf(-(giz + ghz)));
                const float nn = tanhf(gin + rr * ghn);
                const float ho = bf2f(hh[(size_t)grow * Hn + c]) + bf2f(hl[(size_t)grow * Hn + c]);
                const float hv = (1.0f - zz) * nn + zz * ho;
                const ushort_t hi = f2bf(hv);
                const size_t o = ((size_t)s * Bn + grow) * Hn + c;
                Hhi[o] = hi;
                Hlo[o] = f2bf(hv - bf2f(hi));
                if (s == Tn - 1) out_hfin[(size_t)grow * Hn + c] = hv;
            }
            if (s < Tn - 1) grid_bar(bar, NBLK * (unsigned)(s + 1));
        }
    } else {
        const int r0 = (blk - 32) * 16;
        const ushort_t* bh0 = wahh + (size_t)(w * 32 + lr)      * Hn + lg * 8;
        const ushort_t* bh1 = wahh + (size_t)(w * 32 + 16 + lr) * Hn + lg * 8;
        const ushort_t* bl0 = wahl + (size_t)(w * 32 + lr)      * Hn + lg * 8;
        const ushort_t* bl1 = wahl + (size_t)(w * 32 + 16 + lr) * Hn + lg * 8;

        for (int s = 0; s < Tn; s++) {
            const ushort_t* hh = (s == 0) ? zbh : (Hhi + (size_t)(s - 1) * (Bn * Hn));
            const ushort_t* hl = (s == 0) ? zbl : (Hlo + (size_t)(s - 1) * (Bn * Hn));
            const ushort_t* ah = hh + (size_t)(r0 + lr) * Hn + lg * 8;
            const ushort_t* al = hl + (size_t)(r0 + lr) * Hn + lg * 8;

            f32x4 c0a = {0.f,0.f,0.f,0.f}, c1a = {0.f,0.f,0.f,0.f};
            #pragma unroll 2
            for (int ks = 0; ks < 16; ks++) {
                const int k0 = ks * 32;
                const short8v xh  = *reinterpret_cast<const short8v*>(ah + k0);
                const short8v xlo = *reinterpret_cast<const short8v*>(al + k0);
                const short8v w0h = *reinterpret_cast<const short8v*>(bh0 + k0);
                const short8v w1h = *reinterpret_cast<const short8v*>(bh1 + k0);
                const short8v w0l = *reinterpret_cast<const short8v*>(bl0 + k0);
                const short8v w1l = *reinterpret_cast<const short8v*>(bl1 + k0);
                c0a = __builtin_amdgcn_mfma_f32_16x16x32_bf16(xh,  w0h, c0a, 0, 0, 0);
                c0a = __builtin_amdgcn_mfma_f32_16x16x32_bf16(xlo, w0h, c0a, 0, 0, 0);
                c0a = __builtin_amdgcn_mfma_f32_16x16x32_bf16(xh,  w0l, c0a, 0, 0, 0);
                c1a = __builtin_amdgcn_mfma_f32_16x16x32_bf16(xh,  w1h, c1a, 0, 0, 0);
                c1a = __builtin_amdgcn_mfma_f32_16x16x32_bf16(xlo, w1h, c1a, 0, 0, 0);
                c1a = __builtin_amdgcn_mfma_f32_16x16x32_bf16(xh,  w1l, c1a, 0, 0, 0);
            }
            const int jp = (s > 0) ? (s - 1) : 0;
            #pragma unroll
            for (int i = 0; i < 4; i++) {
                const int row = lg * 4 + i;
                const float* gax = Gax + ((size_t)jp * Bn + r0 + row) * Lq;
                lS[row][w * 32 + lr]      = c0a[i] + gax[w * 32 + lr];
                lS[row][w * 32 + 16 + lr] = c1a[i] + gax[w * 32 + 16 + lr];
            }
            __syncthreads();
            {
                const int row = t >> 4, l16 = t & 15;
                float m = -INFINITY;
                #pragma unroll
                for (int kx = 0; kx < 8; kx++) m = fmaxf(m, lS[row][l16 + kx * 16]);
                #pragma unroll
                for (int d = 1; d < 16; d <<= 1) m = fmaxf(m, __shfl_xor(m, d, 16));
                float sv = 0.0f;
                #pragma unroll
                for (int kx = 0; kx < 8; kx++) sv += expf(lS[row][l16 + kx * 16] - m);
                #pragma unroll
                for (int d = 1; d < 16; d <<= 1) sv += __shfl_xor(sv, d, 16);
                const float inv = 1.0f / sv;
                float* oa = out_attn + ((size_t)s * Bn + r0 + row) * Lq;
                #pragma unroll
                for (int kx = 0; kx < 8; kx++)
                    oa[l16 + kx * 16] = expf(lS[row][l16 + kx * 16] - m) * inv;
            }
            __syncthreads();
            if (s < Tn - 1) grid_bar(bar, NBLK * (unsigned)(s + 1));
        }
    }
}

// ---------------------------------------------------------------------------
// big_gemm2: m97-style LDS-staged bf16 MFMA GEMM. Tile 128x128, BK=32,
// 256 threads (4 waves, 2x2 quadrants of 64x64). global_load_lds w16 with
// pre-swizzled source <-> swizzled ds_read_b128 (2-way banks). Epilogue:
// bias + last-step logits + per-block (rowmax, sumexp) partials.
// grid = 250 cb x 64 rb (rb fast: consecutive blocks share the W col-panel).
// ---------------------------------------------------------------------------
__device__ __forceinline__ void stage16(const void* g, void* lds) {
    __builtin_amdgcn_global_load_lds(
        (const __attribute__((address_space(1))) unsigned int*)g,
        (__attribute__((address_space(3))) unsigned int*)lds, 16, 0, 0);
}

__global__ __launch_bounds__(256) void big_gemm2_kernel(
    const ushort_t* __restrict__ Hhi, const ushort_t* __restrict__ wo16,
    const float* __restrict__ bout,
    float* __restrict__ pm, float* __restrict__ ps,
    float* __restrict__ out_logits)
{
    __shared__ ushort_t lA[2][128 * 32];
    __shared__ ushort_t lB[2][128 * 32];
    __shared__ float sm[4][64];
    __shared__ float ssv[4][64];

    const int bid = blockIdx.x;
    const int cb = bid >> 6;       // 0..249
    const int rb = bid & 63;       // 0..63
    const int t = threadIdx.x;
    const int w = t >> 6, l = t & 63;
    const int lr = l & 15, lg = l >> 4;
    const int qr = (w >> 1) * 64;
    const int qc = (w & 1) * 64;
    const int r0 = rb * 128, c0 = cb * 128;

    // staging: thread covers 16B; issue j covers rows j*64 + w*16 .. +16
    const int srow = w * 16 + (l >> 2);             // + j*64
    const int skel = (((l & 3) ^ ((l >> 2) & 3))) * 8;  // swizzled src k-elem
    const ushort_t* gA = Hhi  + (size_t)r0 * Hn;
    const ushort_t* gB = wo16 + (size_t)c0 * Hn;

    f32x4 acc[4][4];
    #pragma unroll
    for (int rt = 0; rt < 4; rt++)
        #pragma unroll
        for (int ct = 0; ct < 4; ct++)
            acc[rt][ct] = (f32x4){0.f, 0.f, 0.f, 0.f};

    // prologue stage ks=0 into buf 0
    #pragma unroll
    for (int j = 0; j < 2; j++) {
        const int row = j * 64 + srow;
        stage16(gA + (size_t)row * Hn + skel, &lA[0][(size_t)(j * 64 + w * 16) * 32]);
        stage16(gB + (size_t)row * Hn + skel, &lB[0][(size_t)(j * 64 + w * 16) * 32]);
    }

    int buf = 0;
    for (int ks = 0; ks < 16; ks++) {
        __syncthreads();                       // staged data ready; prev reads done
        if (ks < 15) {
            const int k0 = (ks + 1) * 32;
            #pragma unroll
            for (int j = 0; j < 2; j++) {
                const int row = j * 64 + srow;
                stage16(gA + (size_t)row * Hn + k0 + skel, &lA[buf ^ 1][(size_t)(j * 64 + w * 16) * 32]);
                stage16(gB + (size_t)row * Hn + k0 + skel, &lB[buf ^ 1][(size_t)(j * 64 + w * 16) * 32]);
            }
        }
        short8v a[4], b[4];
        #pragma unroll
        for (int rt = 0; rt < 4; rt++) {
            const int row = qr + rt * 16 + lr;
            a[rt] = *reinterpret_cast<const short8v*>(&lA[buf][row * 32 + ((lg ^ (row & 3)) * 8)]);
        }
        #pragma unroll
        for (int ct = 0; ct < 4; ct++) {
            const int row = qc + ct * 16 + lr;
            b[ct] = *reinterpret_cast<const short8v*>(&lB[buf][row * 32 + ((lg ^ (row & 3)) * 8)]);
        }
        #pragma unroll
        for (int rt = 0; rt < 4; rt++)
            #pragma unroll
            for (int ct = 0; ct < 4; ct++)
                acc[rt][ct] = __builtin_amdgcn_mfma_f32_16x16x32_bf16(a[rt], b[ct], acc[rt][ct], 0, 0, 0);
        buf ^= 1;
    }

    // epilogue
    float biav[4];
    #pragma unroll
    for (int ct = 0; ct < 4; ct++) biav[ct] = bout[c0 + qc + ct * 16 + lr];

    #pragma unroll
    for (int rt = 0; rt < 4; rt++) {
        #pragma unroll
        for (int i = 0; i < 4; i++) {
            const int rowl_w = rt * 16 + lg * 4 + i;     // 0..63 within wave rows
            const int grow = r0 + qr + rowl_w;
            float v[4];
            #pragma unroll
            for (int ct = 0; ct < 4; ct++) v[ct] = acc[rt][ct][i] + biav[ct];
            if (grow >= MR - Bn && grow < MR) {
                const size_t ob = (size_t)(grow - (MR - Bn)) * Vn + c0 + qc + lr;
                out_logits[ob]      = v[0];
                out_logits[ob + 16] = v[1];
                out_logits[ob + 32] = v[2];
                out_logits[ob + 48] = v[3];
            }
            float m = fmaxf(fmaxf(v[0], v[1]), fmaxf(v[2], v[3]));
            #pragma unroll
            for (int d = 1; d < 16; d <<= 1) m = fmaxf(m, __shfl_xor(m, d));
            float sv = expf(v[0] - m) + expf(v[1] - m) + expf(v[2] - m) + expf(v[3] - m);
            #pragma unroll
            for (int d = 1; d < 16; d <<= 1) sv += __shfl_xor(sv, d);
            if (lr == 0) { sm[w][rowl_w] = m; ssv[w][rowl_w] = sv; }
        }
    }
    __syncthreads();
    if (t < 128) {
        const int half = t >> 6, rl = t & 63;
        const int wa = half * 2;
        float M = sm[wa][rl], S = ssv[wa][rl];
        const float m2 = sm[wa + 1][rl], s2 = ssv[wa + 1][rl];
        const float Mn = fmaxf(M, m2);
        S = S * expf(M - Mn) + s2 * expf(m2 - Mn);
        pm[(size_t)cb * MP + r0 + half * 64 + rl] = Mn;
        ps[(size_t)cb * MP + r0 + half * 64 + rl] = S;
    }
}

// ---------------------------------------------------------------------------
// merge_loss: 127 blocks x 256. Merge 250 partials/row, target dot (hi+lo),
// per-step mean CE -> atomicAdd into out[0] (zeroed in setup).
// ---------------------------------------------------------------------------
__global__ __launch_bounds__(256) void merge_loss_kernel(
    const float* __restrict__ pm, const float* __restrict__ ps,
    const ushort_t* __restrict__ Hhi, const ushort_t* __restrict__ Hlo,
    const int* __restrict__ idx, const float* __restrict__ Wout,
    const float* __restrict__ bout, float* __restrict__ out_loss)
{
    const int tt = blockIdx.x;
    const int t = threadIdx.x;
    const int b = t >> 2, q = t & 3;
    const int grow = tt * 64 + b;

    float M = -INFINITY, S = 0.0f;
    for (int p = q; p < NCB2; p += 4) {
        const float m2 = pm[(size_t)p * MP + grow], s2 = ps[(size_t)p * MP + grow];
        const float Mn = fmaxf(M, m2);
        S = S * expf(M - Mn) + s2 * expf(m2 - Mn);
        M = Mn;
    }
    #pragma unroll
    for (int d = 1; d < 4; d <<= 1) {
        const float m2 = __shfl_xor(M, d, 4);
        const float s2 = __shfl_xor(S, d, 4);
        const float Mn = fmaxf(M, m2);
        S = S * expf(M - Mn) + s2 * expf(m2 - Mn);
        M = Mn;
    }

    const int tgt = idx[b * Lq + tt];
    const size_t hb = (size_t)grow * Hn;
    const float* wr_ = Wout + (size_t)tgt * Hn;
    float dot = 0.0f;
    for (int k = q * 128; k < q * 128 + 128; k += 4) {
        #pragma unroll
        for (int j = 0; j < 4; j++) {
            const float hv = bf2f(Hhi[hb + k + j]) + bf2f(Hlo[hb + k + j]);
            dot = fmaf(hv, wr_[k + j], dot);
        }
    }
    #pragma unroll
    for (int d = 1; d < 4; d <<= 1) dot += __shfl_xor(dot, d, 4);

    __shared__ float ce[Bn];
    if (q == 0) ce[b] = -(dot + bout[tgt] - M - logf(S));
    __syncthreads();
    if (t == 0) {
        float s = 0.0f;
        for (int i = 0; i < Bn; i++) s += ce[i];
        atomicAdd(out_loss, s * (1.0f / Bn));
    }
}

// ===========================================================================
extern "C" void kernel_launch(void* const* d_in, const int* in_sizes, int n_in,
                              void* d_out, int out_size, void* d_ws, size_t ws_size,
                              hipStream_t stream) {
    (void)in_sizes; (void)n_in; (void)out_size; (void)ws_size;
    const int*   idx    = (const int*)  d_in[0];
    const float* emb    = (const float*)d_in[3];
    const float* W_attn = (const float*)d_in[4];
    const float* b_attn = (const float*)d_in[5];
    const float* W_ih   = (const float*)d_in[6];
    const float* W_hh   = (const float*)d_in[7];
    const float* b_ih   = (const float*)d_in[8];
    const float* b_hh   = (const float*)d_in[9];
    const float* W_out  = (const float*)d_in[10];
    const float* b_out  = (const float*)d_in[11];

    float* out = (float*)d_out;
    float* out_attn   = out + 1;
    float* out_hfin   = out + 1 + (size_t)Tn * Bn * Lq;
    float* out_logits = out + 1 + (size_t)Tn * Bn * Lq + (size_t)Bn * Hn;

    char* W = (char*)d_ws;
    unsigned* bar   = (unsigned*)(W + WS_BAR);
    ushort_t* zbh   = (ushort_t*)(W + WS_ZBH);
    ushort_t* zbl   = (ushort_t*)(W + WS_ZBL);
    ushort_t* whhh  = (ushort_t*)(W + WS_WHHH);
    ushort_t* whhl  = (ushort_t*)(W + WS_WHHL);
    ushort_t* wahh  = (ushort_t*)(W + WS_WAHH);
    ushort_t* wahl  = (ushort_t*)(W + WS_WAHL);
    ushort_t* Hhi   = (ushort_t*)(W + WS_HHI);
    ushort_t* Hlo   = (ushort_t*)(W + WS_HLO);
    float*    Gi    = (float*)   (W + WS_GI);
    float*    Gax   = (float*)   (W + WS_GAX);
    ushort_t* wo16  = (ushort_t*)(W + WS_WO16);
    float*    pm    = (float*)   (W + WS_PM);
    float*    ps    = (float*)   (W + WS_PS);

    // phase 0: init + weight splits, then recurrence-free GEMMs (Gi, Gax)
    setup_kernel<<<dim3(3584), dim3(256), 0, stream>>>(
        W_hh, W_attn, zbh, zbl, whhh, whhl, wahh, wahl, Hhi, Hlo, bar, out);
    pre_all_kernel<<<dim3(Tn * 12 + Tn), dim3(256), 0, stream>>>(
        idx, emb, W_ih, b_ih, W_attn, b_attn, Gi, Gax);

    // phase 1: persistent recurrence (ONE launch, 127 steps, grid barrier)
    recur_kernel<<<dim3(NBLK), dim3(256), 0, stream>>>(
        zbh, zbl, whhh, whhl, wahh, wahl, Gi, Gax, b_hh,
        Hhi, Hlo, out_attn, out_hfin, bar);

    // phase 2: W_out -> bf16 (aliases Gi region, now dead), then big GEMM
    wout_cvt_kernel<<<dim3(2048), dim3(256), 0, stream>>>(W_out, wo16);
    big_gemm2_kernel<<<dim3(NCB2 * 64), dim3(256), 0, stream>>>(
        Hhi, wo16, b_out, pm, ps, out_logits);

    // phase 3: merge partials + CE (atomicAdd into out[0])
    merge_loss_kernel<<<dim3(Tn), dim3(256), 0, stream>>>(
        pm, ps, Hhi, Hlo, idx, W_out, b_out, out);
}

// Round 7
// 3059.825 us; speedup vs baseline: 7.9435x; 1.1472x over previous
//
#include <hip/hip_runtime.h>
#include <math.h>

// Problem constants
#define Bn 64      // batch
#define Lq 128     // output_length
#define En 512     // emb dim
#define Hn 512     // hidden
#define Vn 32000   // vocab
#define Tn 127     // steps = L-1
#define MR 8128    // Tn*Bn real rows of H_all
#define MP 8192    // padded rows
#define NCB2 250   // big-gemm col blocks (128 cols each)

typedef __attribute__((ext_vector_type(8))) short short8v;  // 8 bf16
typedef __attribute__((ext_vector_type(4))) float f32x4;
typedef __attribute__((ext_vector_type(4))) unsigned int u32x4;
typedef unsigned short ushort_t;

__device__ __forceinline__ ushort_t f2bf(float f) {
    unsigned u = __builtin_bit_cast(unsigned, f);
    u += 0x7fffu + ((u >> 16) & 1u);          // RNE
    return (ushort_t)(u >> 16);
}
__device__ __forceinline__ float bf2f(ushort_t h) {
    return __builtin_bit_cast(float, ((unsigned)h) << 16);
}

// MALL-coherent (cross-XCD) access helpers: sc0 sc1 bypass L0/L2 so no
// cache-maintenance (wbl2/inv) is ever needed -> weights stay L2-resident.
__device__ __forceinline__ u32x4 ld_coh_x4(const void* p) {
    u32x4 r;
    asm volatile("global_load_dwordx4 %0, %1, off sc0 sc1" : "=&v"(r) : "v"(p));
    return r;
}
__device__ __forceinline__ void st_coh_u16(void* p, unsigned v) {
    asm volatile("global_store_short %0, %1, off sc0 sc1" :: "v"(p), "v"(v) : "memory");
}

// ---------------- ws byte offsets ----------------
constexpr size_t WS_FLAGS = 0;                           // 32 x u32 (+pad) = 128
constexpr size_t WS_WHHH  = 128;                         // W_hh hi/lo bf16 [1536][512]
constexpr size_t WS_WHHL  = WS_WHHH + 1572864;
constexpr size_t WS_WAHH  = WS_WHHL + 1572864;           // W_attn[:,512:] hi/lo [128][512]
constexpr size_t WS_WAHL  = WS_WAHH + 131072;
constexpr size_t WS_HHI   = WS_WAHL + 131072;            // H_all bf16 hi [8192][512]
constexpr size_t WS_HLO   = WS_HHI + 8388608;            // H_all bf16 lo
constexpr size_t WS_U     = WS_HLO + 8388608;            // union region base (20,185,216)
// phase-1 view: Gi fp32 [127][64][1536] | Gax fp32 [127][64][128]
constexpr size_t WS_GI    = WS_U;
constexpr size_t WS_GAX   = WS_U + 49938432;             // end ~74.3 MB
// phase-2 view: wo16 bf16 [32000][512] | pm [250][8192] | ps
constexpr size_t WS_WO16  = WS_U;
constexpr size_t WS_PM    = WS_U + 32768000;
constexpr size_t WS_PS    = WS_PM + 8192000;             // end ~69.3 MB

// ---------------------------------------------------------------------------
// setup_kernel: grid 3584 x 256.
//  blocks 0..255   : zero H pad rows, flags, out[0]
//  blocks 256..3583: split W_hh and W_attn[:,512:] into bf16 hi/lo
// ---------------------------------------------------------------------------
__global__ __launch_bounds__(256) void setup_kernel(
    const float* __restrict__ Whh, const float* __restrict__ Wattn,
    ushort_t* __restrict__ whhh, ushort_t* __restrict__ whhl,
    ushort_t* __restrict__ wahh, ushort_t* __restrict__ wahl,
    ushort_t* __restrict__ Hhi, ushort_t* __restrict__ Hlo,
    unsigned* __restrict__ flags, float* __restrict__ out0)
{
    const int blk = blockIdx.x;
    const int t = threadIdx.x;
    if (blk < 256) {
        const int i = blk * 256 + t;
        if (i < Bn * Hn) Hhi[(size_t)MR * Hn + i] = 0;
        else if (i < 2 * Bn * Hn) Hlo[(size_t)MR * Hn + (i - Bn * Hn)] = 0;
        if (blk == 0 && t < 32) flags[t] = 0u;
        if (blk == 0 && t == 32) out0[0] = 0.0f;
    } else {
        const int e = (blk - 256) * 256 + t;
        const int NW = 1536 * 512;
        if (e < NW) {
            const float wv = Whh[e]; const ushort_t h = f2bf(wv);
            whhh[e] = h; whhl[e] = f2bf(wv - bf2f(h));
        } else {
            const int e2 = e - NW;
            if (e2 < 128 * 512) {
                const int r = e2 >> 9, k = e2 & 511;
                const float wv = Wattn[r * 1024 + 512 + k]; const ushort_t h = f2bf(wv);
                wahh[e2] = h; wahl[e2] = f2bf(wv - bf2f(h));
            }
        }
    }
}

// W_out -> bf16 (grid-stride); aliases Gi region (dead after recurrence)
__global__ __launch_bounds__(256) void wout_cvt_kernel(
    const float* __restrict__ Wout, ushort_t* __restrict__ wo16)
{
    const size_t N = (size_t)Vn * Hn;
    for (size_t i = blockIdx.x * 256 + threadIdx.x; i < N; i += (size_t)gridDim.x * 256)
        wo16[i] = f2bf(Wout[i]);
}

// ---------------------------------------------------------------------------
// fp32 tile GEMM body (proven): A = emb[idx[:,ts]], B = Wb rows (first 512
// cols), + bias -> out[ts][64][ldo] tile at cbase.
// ---------------------------------------------------------------------------
#define PA 68
#define PW 132
__device__ void pre_tile(
    const int* __restrict__ idx, const float* __restrict__ emb,
    const float* __restrict__ Wb, int ldw, const float* __restrict__ bias,
    float* __restrict__ outp, int ldo, int ts, int cbase,
    float* As, float* Ws)
{
    const int t  = threadIdx.x;
    const int tr = t >> 4, tc = t & 15;

    float acc[4][8];
    #pragma unroll
    for (int q = 0; q < 4; q++)
        #pragma unroll
        for (int j = 0; j < 8; j++) acc[q][j] = 0.0f;

    const int ab = t & 63, kq = t >> 6;
    const int wc = t >> 1, wh = t & 1;

    for (int k0 = 0; k0 < 512; k0 += 32) {
        {
            const float* ap = emb + (size_t)idx[ab * Lq + ts] * En + k0 + kq * 8;
            const float4 v0 = *reinterpret_cast<const float4*>(ap);
            const float4 v1 = *reinterpret_cast<const float4*>(ap + 4);
            const int kk = kq * 8;
            As[(kk + 0) * PA + ab] = v0.x;  As[(kk + 1) * PA + ab] = v0.y;
            As[(kk + 2) * PA + ab] = v0.z;  As[(kk + 3) * PA + ab] = v0.w;
            As[(kk + 4) * PA + ab] = v1.x;  As[(kk + 5) * PA + ab] = v1.y;
            As[(kk + 6) * PA + ab] = v1.z;  As[(kk + 7) * PA + ab] = v1.w;
        }
        {
            const float* wp = Wb + (size_t)(cbase + wc) * ldw + k0 + wh * 16;
            const float4 w0 = reinterpret_cast<const float4*>(wp)[0];
            const float4 w1 = reinterpret_cast<const float4*>(wp)[1];
            const float4 w2 = reinterpret_cast<const float4*>(wp)[2];
            const float4 w3 = reinterpret_cast<const float4*>(wp)[3];
            const int kk = wh * 16;
            Ws[(kk + 0 ) * PW + wc] = w0.x; Ws[(kk + 1 ) * PW + wc] = w0.y;
            Ws[(kk + 2 ) * PW + wc] = w0.z; Ws[(kk + 3 ) * PW + wc] = w0.w;
            Ws[(kk + 4 ) * PW + wc] = w1.x; Ws[(kk + 5 ) * PW + wc] = w1.y;
            Ws[(kk + 6 ) * PW + wc] = w1.z; Ws[(kk + 7 ) * PW + wc] = w1.w;
            Ws[(kk + 8 ) * PW + wc] = w2.x; Ws[(kk + 9 ) * PW + wc] = w2.y;
            Ws[(kk + 10) * PW + wc] = w2.z; Ws[(kk + 11) * PW + wc] = w2.w;
            Ws[(kk + 12) * PW + wc] = w3.x; Ws[(kk + 13) * PW + wc] = w3.y;
            Ws[(kk + 14) * PW + wc] = w3.z; Ws[(kk + 15) * PW + wc] = w3.w;
        }
        __syncthreads();
        #pragma unroll 4
        for (int kk = 0; kk < 32; kk++) {
            const float4 av = *reinterpret_cast<const float4*>(&As[kk * PA + tr * 4]);
            const float4 w0 = *reinterpret_cast<const float4*>(&Ws[kk * PW + tc * 8]);
            const float4 w1 = *reinterpret_cast<const float4*>(&Ws[kk * PW + tc * 8 + 4]);
            const float a0 = av.x, a1 = av.y, a2 = av.z, a3 = av.w;
            const float w[8] = {w0.x, w0.y, w0.z, w0.w, w1.x, w1.y, w1.z, w1.w};
            #pragma unroll
            for (int j = 0; j < 8; j++) {
                acc[0][j] = fmaf(a0, w[j], acc[0][j]);
                acc[1][j] = fmaf(a1, w[j], acc[1][j]);
                acc[2][j] = fmaf(a2, w[j], acc[2][j]);
                acc[3][j] = fmaf(a3, w[j], acc[3][j]);
            }
        }
        __syncthreads();
    }

    #pragma unroll
    for (int q = 0; q < 4; q++) {
        const int row = tr * 4 + q;
        #pragma unroll
        for (int j = 0; j < 8; j++) {
            const int lc = tc * 8 + j;
            outp[((size_t)ts * 64 + row) * ldo + cbase + lc] = acc[q][j] + bias[cbase + lc];
        }
    }
}

// pre_all: blocks 0..1523 -> Gi (12 col-blocks x 127 steps); 1524..1650 -> Gax
__global__ __launch_bounds__(256) void pre_all_kernel(
    const int* __restrict__ idx, const float* __restrict__ emb,
    const float* __restrict__ Wih, const float* __restrict__ bih,
    const float* __restrict__ Wattn, const float* __restrict__ battn,
    float* __restrict__ Gi, float* __restrict__ Gax)
{
    __shared__ float As[32 * PA];
    __shared__ float Ws[32 * PW];
    const int blk = blockIdx.x;
    if (blk < Tn * 12) {
        pre_tile(idx, emb, Wih, 512, bih, Gi, 1536, blk / 12, (blk % 12) * 128, As, Ws);
    } else {
        pre_tile(idx, emb, Wattn, 1024, battn, Gax, 128, blk - Tn * 12, 0, As, Ws);
    }
}

// ---------------------------------------------------------------------------
// recur_kernel: PERSISTENT, grid 36 x 256, one launch for all 127 steps.
//  blocks 0..31 : GRU. block (rq,us)=(blk>>3, blk&7): rows rq*16..+16,
//                 u-cols us*64..+64; wave w owns the matched (r,z,n) gate
//                 triplet at cols u0+w*16..+16 -> gates applied in-register.
//  blocks 32..35: attn. block aq: rows aq*16..+16 + row softmax.
// Cross-block h exchange via sc0/sc1 (MALL-coherent) loads/stores; sync via
// 32 monotonic per-block flags (relaxed agent atomics). L2 never invalidated
// -> weights stay L2-resident all 127 steps.
// ---------------------------------------------------------------------------
__global__ __launch_bounds__(256) void recur_kernel(
    const ushort_t* __restrict__ whhh, const ushort_t* __restrict__ whhl,
    const ushort_t* __restrict__ wahh, const ushort_t* __restrict__ wahl,
    const float* __restrict__ Gi, const float* __restrict__ Gax,
    const float* __restrict__ b_hh,
    ushort_t* __restrict__ Hhi, ushort_t* __restrict__ Hlo,
    float* __restrict__ out_attn, float* __restrict__ out_hfin,
    unsigned* __restrict__ flags)
{
    __shared__ ushort_t lA[16384];        // hi [16][512] swizzled | lo at +16384 bytes
    __shared__ float lS[16][128];

    const int blk = blockIdx.x;
    const int t = threadIdx.x;
    const int w = t >> 6, l = t & 63, lr = l & 15, lg = l >> 4;
    const bool isg = (blk < 32);
    const int r0 = isg ? ((blk >> 3) * 16) : ((blk - 32) * 16);
    const int u0 = isg ? ((blk & 7) * 64) : 0;
    const int c  = u0 + w * 16 + lr;      // GRU output col

    // weight fragment pointers
    const ushort_t *pw0h, *pw1h, *pw2h, *pw0l, *pw1l, *pw2l;
    float bhr = 0.f, bhz = 0.f, bhn = 0.f;
    if (isg) {
        pw0h = whhh + (size_t)(c)        * Hn + lg * 8;
        pw1h = whhh + (size_t)(512 + c)  * Hn + lg * 8;
        pw2h = whhh + (size_t)(1024 + c) * Hn + lg * 8;
        pw0l = whhl + (size_t)(c)        * Hn + lg * 8;
        pw1l = whhl + (size_t)(512 + c)  * Hn + lg * 8;
        pw2l = whhl + (size_t)(1024 + c) * Hn + lg * 8;
        bhr = b_hh[c]; bhz = b_hh[512 + c]; bhn = b_hh[1024 + c];
    } else {
        pw0h = wahh + (size_t)(w * 32 + lr)      * Hn + lg * 8;
        pw1h = wahh + (size_t)(w * 32 + 16 + lr) * Hn + lg * 8;
        pw0l = wahl + (size_t)(w * 32 + lr)      * Hn + lg * 8;
        pw1l = wahl + (size_t)(w * 32 + 16 + lr) * Hn + lg * 8;
        pw2h = pw0h; pw2l = pw0l;         // unused
    }

    // staging geometry: thread t covers row erow = t>>4, cols ecol..ecol+32
    const int erow = t >> 4;
    const int ecol = (t & 15) * 32;
    const int swzw = (erow & 7) << 4;
    const int b0 = erow * 1024 + ecol * 2;

    for (int s = 0; s < Tn; s++) {
        if (s > 0) {
            // ---- wait for all 32 GRU flags >= s ----
            unsigned f = 0xFFFFFFFFu;
            if (l < 32) f = __hip_atomic_load(&flags[l], __ATOMIC_RELAXED, __HIP_MEMORY_SCOPE_AGENT);
            while (__any((int)(f < (unsigned)s))) {
                if (l < 32) f = __hip_atomic_load(&flags[l], __ATOMIC_RELAXED, __HIP_MEMORY_SCOPE_AGENT);
            }
            asm volatile("" ::: "memory");
            // ---- stage h[s-1] rows r0..r0+16 into swizzled LDS (hi|lo) ----
            const size_t gb = ((size_t)(s - 1) * Bn + r0 + erow) * Hn + ecol;
            const u32x4 h0 = ld_coh_x4(Hhi + gb);
            const u32x4 h1 = ld_coh_x4(Hhi + gb + 8);
            const u32x4 h2 = ld_coh_x4(Hhi + gb + 16);
            const u32x4 h3 = ld_coh_x4(Hhi + gb + 24);
            const u32x4 o0 = ld_coh_x4(Hlo + gb);
            const u32x4 o1 = ld_coh_x4(Hlo + gb + 8);
            const u32x4 o2 = ld_coh_x4(Hlo + gb + 16);
            const u32x4 o3 = ld_coh_x4(Hlo + gb + 24);
            asm volatile("s_waitcnt vmcnt(0)" ::: "memory");
            char* dst = (char*)lA;
            *(u32x4*)(dst + ((b0     ) ^ swzw)) = h0;
            *(u32x4*)(dst + ((b0 + 16) ^ swzw)) = h1;
            *(u32x4*)(dst + ((b0 + 32) ^ swzw)) = h2;
            *(u32x4*)(dst + ((b0 + 48) ^ swzw)) = h3;
            *(u32x4*)(dst + 16384 + ((b0     ) ^ swzw)) = o0;
            *(u32x4*)(dst + 16384 + ((b0 + 16) ^ swzw)) = o1;
            *(u32x4*)(dst + 16384 + ((b0 + 32) ^ swzw)) = o2;
            *(u32x4*)(dst + 16384 + ((b0 + 48) ^ swzw)) = o3;
            __syncthreads();
        }

        if (isg) {
            // -------- GRU path --------
            f32x4 a0 = {0.f,0.f,0.f,0.f}, a1 = {0.f,0.f,0.f,0.f}, a2 = {0.f,0.f,0.f,0.f};
            if (s > 0) {
                const int swzr = (lr & 7) << 4;
                #pragma unroll 2
                for (int ks = 0; ks < 16; ks++) {
                    const int ab = (lr * 1024 + ks * 64 + lg * 16) ^ swzr;
                    const short8v xh = *(const short8v*)((char*)lA + ab);
                    const short8v xl = *(const short8v*)((char*)lA + 16384 + ab);
                    const int ko = ks * 32;
                    const short8v w0h = *(const short8v*)(pw0h + ko);
                    const short8v w1h = *(const short8v*)(pw1h + ko);
                    const short8v w2h = *(const short8v*)(pw2h + ko);
                    const short8v w0l = *(const short8v*)(pw0l + ko);
                    const short8v w1l = *(const short8v*)(pw1l + ko);
                    const short8v w2l = *(const short8v*)(pw2l + ko);
                    a0 = __builtin_amdgcn_mfma_f32_16x16x32_bf16(xh, w0h, a0, 0, 0, 0);
                    a0 = __builtin_amdgcn_mfma_f32_16x16x32_bf16(xl, w0h, a0, 0, 0, 0);
                    a0 = __builtin_amdgcn_mfma_f32_16x16x32_bf16(xh, w0l, a0, 0, 0, 0);
                    a1 = __builtin_amdgcn_mfma_f32_16x16x32_bf16(xh, w1h, a1, 0, 0, 0);
                    a1 = __builtin_amdgcn_mfma_f32_16x16x32_bf16(xl, w1h, a1, 0, 0, 0);
                    a1 = __builtin_amdgcn_mfma_f32_16x16x32_bf16(xh, w1l, a1, 0, 0, 0);
                    a2 = __builtin_amdgcn_mfma_f32_16x16x32_bf16(xh, w2h, a2, 0, 0, 0);
                    a2 = __builtin_amdgcn_mfma_f32_16x16x32_bf16(xl, w2h, a2, 0, 0, 0);
                    a2 = __builtin_amdgcn_mfma_f32_16x16x32_bf16(xh, w2l, a2, 0, 0, 0);
                }
            }
            #pragma unroll
            for (int i = 0; i < 4; i++) {
                const int row16 = lg * 4 + i;
                const int grow = r0 + row16;
                const float* gib = Gi + ((size_t)s * Bn + grow) * 1536 + c;
                const float gir = gib[0], giz = gib[512], gin = gib[1024];
                const float ghr = a0[i] + bhr, ghz = a1[i] + bhz, ghn = a2[i] + bhn;
                const float rr = 1.0f / (1.0f + expf(-(gir + ghr)));
                const float zz = 1.0f / (1.0f + expf(-(giz + ghz)));
                const float nn = tanhf(gin + rr * ghn);
                float ho = 0.0f;
                if (s > 0) {
                    const int hb = (row16 * 1024 + c * 2) ^ ((row16 & 7) << 4);
                    ho = bf2f(*(const ushort_t*)((char*)lA + hb))
                       + bf2f(*(const ushort_t*)((char*)lA + 16384 + hb));
                }
                const float hv = (1.0f - zz) * nn + zz * ho;
                const ushort_t hi = f2bf(hv);
                const ushort_t lo = f2bf(hv - bf2f(hi));
                const size_t o = ((size_t)s * Bn + grow) * Hn + c;
                st_coh_u16(Hhi + o, (unsigned)hi);
                st_coh_u16(Hlo + o, (unsigned)lo);
                if (s == Tn - 1) out_hfin[(size_t)grow * Hn + c] = hv;
            }
            asm volatile("s_waitcnt vmcnt(0)" ::: "memory");
            __syncthreads();
            if (t == 0)
                __hip_atomic_store(&flags[blk], (unsigned)(s + 1),
                                   __ATOMIC_RELAXED, __HIP_MEMORY_SCOPE_AGENT);
        } else {
            // -------- attn path --------
            f32x4 c0a = {0.f,0.f,0.f,0.f}, c1a = {0.f,0.f,0.f,0.f};
            if (s > 0) {
                const int swzr = (lr & 7) << 4;
                #pragma unroll 2
                for (int ks = 0; ks < 16; ks++) {
                    const int ab = (lr * 1024 + ks * 64 + lg * 16) ^ swzr;
                    const short8v xh = *(const short8v*)((char*)lA + ab);
                    const short8v xl = *(const short8v*)((char*)lA + 16384 + ab);
                    const int ko = ks * 32;
                    const short8v w0h = *(const short8v*)(pw0h + ko);
                    const short8v w1h = *(const short8v*)(pw1h + ko);
                    const short8v w0l = *(const short8v*)(pw0l + ko);
                    const short8v w1l = *(const short8v*)(pw1l + ko);
                    c0a = __builtin_amdgcn_mfma_f32_16x16x32_bf16(xh, w0h, c0a, 0, 0, 0);
                    c0a = __builtin_amdgcn_mfma_f32_16x16x32_bf16(xl, w0h, c0a, 0, 0, 0);
                    c0a = __builtin_amdgcn_mfma_f32_16x16x32_bf16(xh, w0l, c0a, 0, 0, 0);
                    c1a = __builtin_amdgcn_mfma_f32_16x16x32_bf16(xh, w1h, c1a, 0, 0, 0);
                    c1a = __builtin_amdgcn_mfma_f32_16x16x32_bf16(xl, w1h, c1a, 0, 0, 0);
                    c1a = __builtin_amdgcn_mfma_f32_16x16x32_bf16(xh, w1l, c1a, 0, 0, 0);
                }
            }
            const int jp = (s > 0) ? (s - 1) : 0;
            #pragma unroll
            for (int i = 0; i < 4; i++) {
                const int row = lg * 4 + i;
                const float* gax = Gax + ((size_t)jp * Bn + r0 + row) * Lq;
                lS[row][w * 32 + lr]      = c0a[i] + gax[w * 32 + lr];
                lS[row][w * 32 + 16 + lr] = c1a[i] + gax[w * 32 + 16 + lr];
            }
            __syncthreads();
            {
                const int row = t >> 4, l16 = t & 15;
                float m = -INFINITY;
                #pragma unroll
                for (int kx = 0; kx < 8; kx++) m = fmaxf(m, lS[row][l16 + kx * 16]);
                #pragma unroll
                for (int d = 1; d < 16; d <<= 1) m = fmaxf(m, __shfl_xor(m, d, 16));
                float sv = 0.0f;
                #pragma unroll
                for (int kx = 0; kx < 8; kx++) sv += expf(lS[row][l16 + kx * 16] - m);
                #pragma unroll
                for (int d = 1; d < 16; d <<= 1) sv += __shfl_xor(sv, d, 16);
                const float inv = 1.0f / sv;
                float* oa = out_attn + ((size_t)s * Bn + r0 + row) * Lq;
                #pragma unroll
                for (int kx = 0; kx < 8; kx++)
                    oa[l16 + kx * 16] = expf(lS[row][l16 + kx * 16] - m) * inv;
            }
            __syncthreads();
        }
    }
}

// ---------------------------------------------------------------------------
// big_gemm2: LDS-staged bf16 MFMA GEMM, tile 128x128 BK=32 double-buffered,
// global_load_lds w16 with pre-swizzled source <-> swizzled ds_read_b128
// (2-way banks). Epilogue: bias + last-step logits + (rowmax, sumexp).
// grid = 250 cb x 64 rb (rb fast: consecutive blocks share the W col-panel).
// ---------------------------------------------------------------------------
__device__ __forceinline__ void stage16(const void* g, void* lds) {
    __builtin_amdgcn_global_load_lds(
        (const __attribute__((address_space(1))) unsigned int*)g,
        (__attribute__((address_space(3))) unsigned int*)lds, 16, 0, 0);
}

__global__ __launch_bounds__(256) void big_gemm2_kernel(
    const ushort_t* __restrict__ Hhi, const ushort_t* __restrict__ wo16,
    const float* __restrict__ bout,
    float* __restrict__ pm, float* __restrict__ ps,
    float* __restrict__ out_logits)
{
    __shared__ ushort_t lA[2][128 * 32];
    __shared__ ushort_t lB[2][128 * 32];
    __shared__ float sm[4][64];
    __shared__ float ssv[4][64];

    const int bid = blockIdx.x;
    const int cb = bid >> 6;       // 0..249
    const int rb = bid & 63;       // 0..63
    const int t = threadIdx.x;
    const int w = t >> 6, l = t & 63;
    const int lr = l & 15, lg = l >> 4;
    const int qr = (w >> 1) * 64;
    const int qc = (w & 1) * 64;
    const int r0 = rb * 128, c0 = cb * 128;

    const int srow = w * 16 + (l >> 2);                    // + j*64
    const int skel = (((l & 3) ^ ((l >> 3) & 3))) * 8;     // pre-swizzled src k-elem
    const ushort_t* gA = Hhi  + (size_t)r0 * Hn;
    const ushort_t* gB = wo16 + (size_t)c0 * Hn;

    f32x4 acc[4][4];
    #pragma unroll
    for (int rt = 0; rt < 4; rt++)
        #pragma unroll
        for (int ct = 0; ct < 4; ct++)
            acc[rt][ct] = (f32x4){0.f, 0.f, 0.f, 0.f};

    #pragma unroll
    for (int j = 0; j < 2; j++) {
        const int row = j * 64 + srow;
        stage16(gA + (size_t)row * Hn + skel, &lA[0][(size_t)(j * 64 + w * 16) * 32]);
        stage16(gB + (size_t)row * Hn + skel, &lB[0][(size_t)(j * 64 + w * 16) * 32]);
    }

    int buf = 0;
    for (int ks = 0; ks < 16; ks++) {
        __syncthreads();
        if (ks < 15) {
            const int k0 = (ks + 1) * 32;
            #pragma unroll
            for (int j = 0; j < 2; j++) {
                const int row = j * 64 + srow;
                stage16(gA + (size_t)row * Hn + k0 + skel, &lA[buf ^ 1][(size_t)(j * 64 + w * 16) * 32]);
                stage16(gB + (size_t)row * Hn + k0 + skel, &lB[buf ^ 1][(size_t)(j * 64 + w * 16) * 32]);
            }
        }
        short8v a[4], b[4];
        #pragma unroll
        for (int rt = 0; rt < 4; rt++) {
            const int row = qr + rt * 16 + lr;
            a[rt] = *reinterpret_cast<const short8v*>(&lA[buf][row * 32 + ((lg ^ ((row >> 1) & 3)) * 8)]);
        }
        #pragma unroll
        for (int ct = 0; ct < 4; ct++) {
            const int row = qc + ct * 16 + lr;
            b[ct] = *reinterpret_cast<const short8v*>(&lB[buf][row * 32 + ((lg ^ ((row >> 1) & 3)) * 8)]);
        }
        #pragma unroll
        for (int rt = 0; rt < 4; rt++)
            #pragma unroll
            for (int ct = 0; ct < 4; ct++)
                acc[rt][ct] = __builtin_amdgcn_mfma_f32_16x16x32_bf16(a[rt], b[ct], acc[rt][ct], 0, 0, 0);
        buf ^= 1;
    }

    float biav[4];
    #pragma unroll
    for (int ct = 0; ct < 4; ct++) biav[ct] = bout[c0 + qc + ct * 16 + lr];

    #pragma unroll
    for (int rt = 0; rt < 4; rt++) {
        #pragma unroll
        for (int i = 0; i < 4; i++) {
            const int rowl_w = rt * 16 + lg * 4 + i;
            const int grow = r0 + qr + rowl_w;
            float v[4];
            #pragma unroll
            for (int ct = 0; ct < 4; ct++) v[ct] = acc[rt][ct][i] + biav[ct];
            if (grow >= MR - Bn && grow < MR) {
                const size_t ob = (size_t)(grow - (MR - Bn)) * Vn + c0 + qc + lr;
                out_logits[ob]      = v[0];
                out_logits[ob + 16] = v[1];
                out_logits[ob + 32] = v[2];
                out_logits[ob + 48] = v[3];
            }
            float m = fmaxf(fmaxf(v[0], v[1]), fmaxf(v[2], v[3]));
            #pragma unroll
            for (int d = 1; d < 16; d <<= 1) m = fmaxf(m, __shfl_xor(m, d));
            float sv = expf(v[0] - m) + expf(v[1] - m) + expf(v[2] - m) + expf(v[3] - m);
            #pragma unroll
            for (int d = 1; d < 16; d <<= 1) sv += __shfl_xor(sv, d);
            if (lr == 0) { sm[w][rowl_w] = m; ssv[w][rowl_w] = sv; }
        }
    }
    __syncthreads();
    if (t < 128) {
        const int half = t >> 6, rl = t & 63;
        const int wa = half * 2;
        float M = sm[wa][rl], S = ssv[wa][rl];
        const float m2 = sm[wa + 1][rl], s2 = ssv[wa + 1][rl];
        const float Mn = fmaxf(M, m2);
        S = S * expf(M - Mn) + s2 * expf(m2 - Mn);
        pm[(size_t)cb * MP + r0 + half * 64 + rl] = Mn;
        ps[(size_t)cb * MP + r0 + half * 64 + rl] = S;
    }
}

// ---------------------------------------------------------------------------
// merge_loss: 127 blocks x 256. Merge 250 partials/row, target dot (hi+lo),
// per-step mean CE -> atomicAdd into out[0] (zeroed in setup).
// ---------------------------------------------------------------------------
__global__ __launch_bounds__(256) void merge_loss_kernel(
    const float* __restrict__ pm, const float* __restrict__ ps,
    const ushort_t* __restrict__ Hhi, const ushort_t* __restrict__ Hlo,
    const int* __restrict__ idx, const float* __restrict__ Wout,
    const float* __restrict__ bout, float* __restrict__ out_loss)
{
    const int tt = blockIdx.x;
    const int t = threadIdx.x;
    const int b = t >> 2, q = t & 3;
    const int grow = tt * 64 + b;

    float M = -INFINITY, S = 0.0f;
    for (int p = q; p < NCB2; p += 4) {
        const float m2 = pm[(size_t)p * MP + grow], s2 = ps[(size_t)p * MP + grow];
        const float Mn = fmaxf(M, m2);
        S = S * expf(M - Mn) + s2 * expf(m2 - Mn);
        M = Mn;
    }
    #pragma unroll
    for (int d = 1; d < 4; d <<= 1) {
        const float m2 = __shfl_xor(M, d, 4);
        const float s2 = __shfl_xor(S, d, 4);
        const float Mn = fmaxf(M, m2);
        S = S * expf(M - Mn) + s2 * expf(m2 - Mn);
        M = Mn;
    }

    const int tgt = idx[b * Lq + tt];
    const size_t hb = (size_t)grow * Hn;
    const float* wr_ = Wout + (size_t)tgt * Hn;
    float dot = 0.0f;
    for (int k = q * 128; k < q * 128 + 128; k += 4) {
        #pragma unroll
        for (int j = 0; j < 4; j++) {
            const float hv = bf2f(Hhi[hb + k + j]) + bf2f(Hlo[hb + k + j]);
            dot = fmaf(hv, wr_[k + j], dot);
        }
    }
    #pragma unroll
    for (int d = 1; d < 4; d <<= 1) dot += __shfl_xor(dot, d, 4);

    __shared__ float ce[Bn];
    if (q == 0) ce[b] = -(dot + bout[tgt] - M - logf(S));
    __syncthreads();
    if (t == 0) {
        float s = 0.0f;
        for (int i = 0; i < Bn; i++) s += ce[i];
        atomicAdd(out_loss, s * (1.0f / Bn));
    }
}

// ===========================================================================
extern "C" void kernel_launch(void* const* d_in, const int* in_sizes, int n_in,
                              void* d_out, int out_size, void* d_ws, size_t ws_size,
                              hipStream_t stream) {
    (void)in_sizes; (void)n_in; (void)out_size; (void)ws_size;
    const int*   idx    = (const int*)  d_in[0];
    const float* emb    = (const float*)d_in[3];
    const float* W_attn = (const float*)d_in[4];
    const float* b_attn = (const float*)d_in[5];
    const float* W_ih   = (const float*)d_in[6];
    const float* W_hh   = (const float*)d_in[7];
    const float* b_ih   = (const float*)d_in[8];
    const float* b_hh   = (const float*)d_in[9];
    const float* W_out  = (const float*)d_in[10];
    const float* b_out  = (const float*)d_in[11];

    float* out = (float*)d_out;
    float* out_attn   = out + 1;
    float* out_hfin   = out + 1 + (size_t)Tn * Bn * Lq;
    float* out_logits = out + 1 + (size_t)Tn * Bn * Lq + (size_t)Bn * Hn;

    char* W = (char*)d_ws;
    unsigned* flags = (unsigned*)(W + WS_FLAGS);
    ushort_t* whhh  = (ushort_t*)(W + WS_WHHH);
    ushort_t* whhl  = (ushort_t*)(W + WS_WHHL);
    ushort_t* wahh  = (ushort_t*)(W + WS_WAHH);
    ushort_t* wahl  = (ushort_t*)(W + WS_WAHL);
    ushort_t* Hhi   = (ushort_t*)(W + WS_HHI);
    ushort_t* Hlo   = (ushort_t*)(W + WS_HLO);
    float*    Gi    = (float*)   (W + WS_GI);
    float*    Gax   = (float*)   (W + WS_GAX);
    ushort_t* wo16  = (ushort_t*)(W + WS_WO16);
    float*    pm    = (float*)   (W + WS_PM);
    float*    ps    = (float*)   (W + WS_PS);

    // phase 0: init + weight splits; recurrence-free GEMMs (Gi, Gax)
    setup_kernel<<<dim3(3584), dim3(256), 0, stream>>>(
        W_hh, W_attn, whhh, whhl, wahh, wahl, Hhi, Hlo, flags, out);
    pre_all_kernel<<<dim3(Tn * 12 + Tn), dim3(256), 0, stream>>>(
        idx, emb, W_ih, b_ih, W_attn, b_attn, Gi, Gax);

    // phase 1: persistent recurrence (ONE launch, flag-based sync)
    recur_kernel<<<dim3(36), dim3(256), 0, stream>>>(
        whhh, whhl, wahh, wahl, Gi, Gax, b_hh,
        Hhi, Hlo, out_attn, out_hfin, flags);

    // phase 2: W_out -> bf16 (aliases Gi region, now dead), then big GEMM
    wout_cvt_kernel<<<dim3(2048), dim3(256), 0, stream>>>(W_out, wo16);
    big_gemm2_kernel<<<dim3(NCB2 * 64), dim3(256), 0, stream>>>(
        Hhi, wo16, b_out, pm, ps, out_logits);

    // phase 3: merge partials + CE (atomicAdd into out[0])
    merge_loss_kernel<<<dim3(Tn), dim3(256), 0, stream>>>(
        pm, ps, Hhi, Hlo, idx, W_out, b_out, out);
}